// Round 3
// baseline (616.748 us; speedup 1.0000x reference)
//
#include <hip/hip_runtime.h>
#include <hip/hip_bf16.h>
#include <math.h>

// Problem constants (fixed by setup_inputs)
#define NS   2
#define NVIN 3
#define NVT  4
#define NC   16
#define ND   64
#define NH   96
#define NW   96
#define HWH  48          // half res h=w
#define SPR  64
#define DHW  (ND*NH*NW)  // 589824
#define NTILE (DHW / 64) // 9216 — NOT a power of two
#define NSAMP (NS*NVT*HWH*HWH*SPR)   // 1179648 samples
#define NRAYS (NS*NVT*HWH*HWH)       // 18432 (% 8 == 0)

typedef __attribute__((ext_vector_type(8))) short bfrag;   // 8 bf16 (4 VGPR)
typedef __attribute__((ext_vector_type(4))) float cfrag;   // 4 fp32 acc

#define MFMA16 __builtin_amdgcn_mfma_f32_16x16x32_bf16

// Wave-local LDS ordering: each wave's sbuf slice is private, so a block
// barrier is never needed — only completion/ordering of THIS wave's DS ops.
// DS ops from one wave are processed in order by the LDS pipe; the asm
// "memory" clobber pins compiler-level ordering of surrounding LDS accesses.
// (R1 lesson: do NOT fuse the latency-bound gather into this kernel — it
// needs 80% occupancy; this kernel runs at ~22%.)
#define WAVE_LDS_SYNC() asm volatile("s_waitcnt lgkmcnt(0)" ::: "memory")

__device__ __forceinline__ short f2bf(float x) {
    union { __hip_bfloat16 b; short s; } cv;
    cv.b = __float2bfloat16(x);
    return cv.s;
}
__device__ __forceinline__ float bf2f(short s) {
    union { unsigned int u; float f; } cv;
    cv.u = ((unsigned int)(unsigned short)s) << 16;
    return cv.f;
}

// Build hi/lo bf16 A-fragment from 8 consecutive fp32 (LDS or global).
// Verified layout (m120): A[m=lane&15][k=(lane>>4)*8+j], j=0..7.
__device__ __forceinline__ void mk_frag(const float* p, bfrag& ah, bfrag& al) {
    float4 v0 = *(const float4*)p;
    float4 v1 = *(const float4*)(p + 4);
    float e[8] = {v0.x, v0.y, v0.z, v0.w, v1.x, v1.y, v1.z, v1.w};
    #pragma unroll
    for (int j = 0; j < 8; j++) {
        short h = f2bf(e[j]);
        ah[j] = h;
        al[j] = f2bf(e[j] - bf2f(h));
    }
}

// ---------------------------------------------------------------------------
// Weight-fragment prep (R7-verified): split W1/W2/W3 into bf16 hi/lo,
// fragment-linear so each lane loads its B-fragment with one dwordx4.
// ---------------------------------------------------------------------------
__global__ __launch_bounds__(256) void wprep_kernel(
    const float* __restrict__ W1, const float* __restrict__ W2,
    const float* __restrict__ W3, short* __restrict__ whi, short* __restrict__ wlo)
{
    int t = blockIdx.x * 256 + threadIdx.x;   // 1024 total
    int f = t >> 6, L = t & 63;
    int q = L >> 4, li = L & 15;
    #pragma unroll
    for (int j = 0; j < 8; j++) {
        int kloc = q * 8 + j;                 // 0..31
        float w = 0.f;
        if (f < 4) {
            int n = f * 16 + li, k = kloc;
            if (k < 16) w = W1[k * 64 + n];
        } else if (f < 12) {
            int kt = (f - 4) >> 2, nt = (f - 4) & 3;
            w = W2[(kt * 32 + kloc) * 64 + nt * 16 + li];
        } else {
            int kt = (f - 12) >> 1, nt = (f - 12) & 1;
            int n = nt * 16 + li;
            if (n < 17) w = W3[(kt * 32 + kloc) * 17 + n];
        }
        short h = f2bf(w);
        whi[(f * 64 + L) * 8 + j] = h;
        wlo[(f * 64 + L) * 8 + j] = f2bf(w - bf2f(h));
    }
}

// ---------------------------------------------------------------------------
// LDS-tiled transpose enc [6][16][DHW] -> enc_t [6][DHW][16].
// ---------------------------------------------------------------------------
__global__ __launch_bounds__(256) void transpose_kernel(
    const float* __restrict__ in, float* __restrict__ out)
{
    __shared__ float tile[NC][64 + 4];
    const int t   = threadIdx.x;
    const int blk = blockIdx.x;
    const int vox0 = (blk % NTILE) * 64;
    const int sv   = blk / NTILE;

    const int c  = t >> 4;
    const int vg = (t & 15) * 4;
    const float* src = in + ((size_t)sv * NC + c) * DHW + vox0 + vg;
    float4 v = *(const float4*)src;
    tile[c][vg + 0] = v.x; tile[c][vg + 1] = v.y;
    tile[c][vg + 2] = v.z; tile[c][vg + 3] = v.w;
    __syncthreads();

    const int ov = t >> 2;
    const int oc = (t & 3) * 4;
    float4 w = make_float4(tile[oc + 0][ov], tile[oc + 1][ov],
                           tile[oc + 2][ov], tile[oc + 3][ov]);
    float* dst = out + ((size_t)sv * DHW + vox0 + ov) * NC + oc;
    *(float4*)dst = w;
}

// ---------------------------------------------------------------------------
// Quad-cooperative gather: 4 lanes per sample, lane c4 loads channels
// 4*c4..4*c4+3 (16 B). A quad's 4 loads hit ONE 64 B voxel line.
// R3 changes (both correctness-neutral):
//  * XCD-chunked ray swizzle: each XCD gets one contiguous target image
//    (2304 rays), so concurrently-resident rays on an XCD are spatially
//    adjacent -> voxel lines reused within one L2 instead of fetched by 8.
//  * Per-axis trilinear hoist: weights/valid/clamped-indices/row-offsets
//    computed once per (sample,view); the 8-corner loop is {1 add, 2 mul,
//    4 fmac} per corner. Bit-identical (same product association, per-axis
//    validity-zeroing == per-corner zeroing).
// ---------------------------------------------------------------------------
__global__ __launch_bounds__(256) void gather_kernel(
    const float* __restrict__ enc_t,
    const float* __restrict__ ipose,
    const float* __restrict__ tpose,
    const float* __restrict__ focal_p,
    const float* __restrict__ znear_p,
    const float* __restrict__ zfar_p,
    float* __restrict__ xbuf)
{
    // one block == one ray (256 threads = 64 depth samples x 4 channel-quads)
    const int ray = (blockIdx.x & 7) * (NRAYS >> 3) + (blockIdx.x >> 3);
    const int c4  = threadIdx.x & 3;
    const int d   = threadIdx.x >> 2;    // depth sample 0..63
    const int px  = ray % HWH;
    const int py  = (ray / HWH) % HWH;
    const int b   = ray / (HWH * HWH);
    const int s   = b >> 2;

    const float focal = focal_p[0];
    const float znear = znear_p[0];
    const float zfar  = zfar_p[0];

    const float* P = tpose + b * 16;
    float ysc = ((py + 0.5f) / (float)HWH) * 2.f - 1.f;
    float xsc = ((px + 0.5f) / (float)HWH) * 2.f - 1.f;
    float dcx = xsc / focal, dcy = -ysc / focal, dcz = -1.f;
    float dirx = P[0]*dcx + P[1]*dcy + P[2]*dcz;
    float diry = P[4]*dcx + P[5]*dcy + P[6]*dcz;
    float dirz = P[8]*dcx + P[9]*dcy + P[10]*dcz;

    float tv  = znear + (zfar - znear) * ((float)d / (float)(SPR - 1));
    float ptx = P[3] + tv * dirx, pty = P[7] + tv * diry, ptz = P[11] + tv * dirz;

    const float minz = focal * znear, maxz = focal * zfar;
    float f0 = 0.f, f1 = 0.f, f2 = 0.f, f3 = 0.f;

    #pragma unroll
    for (int v = 0; v < NVIN; v++) {
        const float* E = ipose + (s * NVIN + v) * 16;
        float qx = ptx - E[3], qy = pty - E[7], qz = ptz - E[11];
        float lx = E[0]*qx + E[4]*qy + E[8]*qz;
        float ly = E[1]*qx + E[5]*qy + E[9]*qz;
        float lz = E[2]*qx + E[6]*qy + E[10]*qz;
        float zz = -lz;
        float u  = lx / zz * focal;
        float vv = ly / zz * focal;
        float wd = 2.f * (zz - minz) / (maxz - minz) - 1.f;
        float ix = ((u   + 1.f) * NW - 1.f) * 0.5f;
        float iy = ((-vv + 1.f) * NH - 1.f) * 0.5f;
        float iz = ((-wd + 1.f) * ND - 1.f) * 0.5f;
        float x0 = floorf(ix), y0 = floorf(iy), z0 = floorf(iz);
        float x1 = x0 + 1.f,   y1 = y0 + 1.f,   z1 = z0 + 1.f;

        // per-axis weights (exactly 1 - |i - corner|, as before)
        float wxa0 = 1.f - fabsf(ix - x0), wxa1 = 1.f - fabsf(ix - x1);
        float wya0 = 1.f - fabsf(iy - y0), wya1 = 1.f - fabsf(iy - y1);
        float wza0 = 1.f - fabsf(iz - z0), wza1 = 1.f - fabsf(iz - z1);
        // per-axis validity zeroing (== old per-corner zeroing of the product)
        wxa0 = (x0 >= 0.f && x0 < (float)NW) ? wxa0 : 0.f;
        wxa1 = (x1 >= 0.f && x1 < (float)NW) ? wxa1 : 0.f;
        wya0 = (y0 >= 0.f && y0 < (float)NH) ? wya0 : 0.f;
        wya1 = (y1 >= 0.f && y1 < (float)NH) ? wya1 : 0.f;
        wza0 = (z0 >= 0.f && z0 < (float)ND) ? wza0 : 0.f;
        wza1 = (z1 >= 0.f && z1 < (float)ND) ? wza1 : 0.f;
        // per-axis clamped indices
        int xi0 = min(max((int)x0, 0), NW - 1), xi1 = min(max((int)x1, 0), NW - 1);
        int yi0 = min(max((int)y0, 0), NH - 1), yi1 = min(max((int)y1, 0), NH - 1);
        int zi0 = min(max((int)z0, 0), ND - 1), zi1 = min(max((int)z1, 0), ND - 1);
        // (z,y) row offsets
        int o00 = (zi0 * NH + yi0) * NW, o01 = (zi0 * NH + yi1) * NW;
        int o10 = (zi1 * NH + yi0) * NW, o11 = (zi1 * NH + yi1) * NW;

        const float wxv[2] = {wxa0, wxa1};
        const float wyv[2] = {wya0, wya1};
        const float wzv[2] = {wza0, wza1};
        const int   xiv[2] = {xi0, xi1};
        const int   ozy[2][2] = {{o00, o01}, {o10, o11}};

        const float* VB = enc_t + (size_t)(s * NVIN + v) * DHW * NC;
        #pragma unroll
        for (int k = 0; k < 8; k++) {
            const int dx = k & 1, dy = (k >> 1) & 1, dz = k >> 2;
            float w = (wxv[dx] * wyv[dy]) * wzv[dz];   // same association as old
            int idx = ozy[dz][dy] + xiv[dx];
            float4 a = *(const float4*)(VB + (size_t)idx * NC + c4 * 4);
            f0 += w * a.x; f1 += w * a.y; f2 += w * a.z; f3 += w * a.w;
        }
    }
    const float inv3 = 1.f / 3.f;
    ((float4*)xbuf)[(ray * 64 + d) * 4 + c4] =
        make_float4(f0 * inv3, f1 * inv3, f2 * inv3, f3 * inv3);
}

// ---------------------------------------------------------------------------
// MFMA MLP + composite (R7-verified pipeline, A-frags from global xbuf).
// One wave per ray; block = 4 rays. bf16 hi/lo 3-product = fp32-accurate.
// R2: sbuf slices are per-wave, so every __syncthreads() is replaced by a
// wave-local lgkmcnt(0) — zero cross-wave barriers (verified win).
// ---------------------------------------------------------------------------
__global__ __launch_bounds__(256) void mlp_kernel(
    const float* __restrict__ xbuf,
    const float* __restrict__ znear_p,
    const float* __restrict__ zfar_p,
    const short* __restrict__ whi, const short* __restrict__ wlo,
    const float* __restrict__ B1, const float* __restrict__ B2,
    const float* __restrict__ B3,
    float* __restrict__ rhalf)
{
    const int lane = threadIdx.x & 63;
    const int ray  = blockIdx.x * 4 + (threadIdx.x >> 6);
    const int px   = ray % HWH;
    const int py   = (ray / HWH) % HWH;
    const int b    = ray / (HWH * HWH);

    const float znear = znear_p[0];
    const float zfar  = zfar_p[0];

    __shared__ float sbuf[4][64][36];   // per-wave 64x36 staging (36.9 KB)
    float (*B)[36] = sbuf[threadIdx.x >> 6];
    const int li = lane & 15, q = lane >> 4;
    const float* X = xbuf + (size_t)ray * 64 * NC;   // this ray's 64x16 rows

    float b1v[4], b2v[4], b3v[2];
    #pragma unroll
    for (int nt = 0; nt < 4; nt++) { b1v[nt] = B1[nt*16 + li]; b2v[nt] = B2[nt*16 + li]; }
    b3v[0] = B3[li];
    b3v[1] = (li == 0) ? B3[16] : 0.f;

    // layer-1 A-frags straight from global X (K=16; q>=2 lanes are zero pad)
    bfrag xah[4], xal[4];
    bfrag zb = {0,0,0,0,0,0,0,0};
    #pragma unroll
    for (int mt = 0; mt < 4; mt++) {
        if (q < 2) mk_frag(X + (mt*16 + li) * NC + q * 8, xah[mt], xal[mt]);
        else { xah[mt] = zb; xal[mt] = zb; }
    }

    cfrag zc = {0.f, 0.f, 0.f, 0.f};
    cfrag h2acc[4][4];
    #pragma unroll
    for (int mt = 0; mt < 4; mt++)
        #pragma unroll
        for (int nt = 0; nt < 4; nt++) h2acc[mt][nt] = zc;

    #pragma unroll
    for (int c1 = 0; c1 < 2; c1++) {
        cfrag h1[4][2];
        #pragma unroll
        for (int nt2 = 0; nt2 < 2; nt2++) {
            int f = 2*c1 + nt2;
            bfrag bh = *(const bfrag*)(whi + (f*64 + lane)*8);
            bfrag bl = *(const bfrag*)(wlo + (f*64 + lane)*8);
            #pragma unroll
            for (int mt = 0; mt < 4; mt++) {
                cfrag a = zc;
                a = MFMA16(xal[mt], bh, a, 0, 0, 0);
                a = MFMA16(xah[mt], bl, a, 0, 0, 0);
                a = MFMA16(xah[mt], bh, a, 0, 0, 0);
                h1[mt][nt2] = a;
            }
        }
        WAVE_LDS_SYNC();   // prior iter's staging reads ordered before writes
        #pragma unroll
        for (int mt = 0; mt < 4; mt++)
            #pragma unroll
            for (int nt2 = 0; nt2 < 2; nt2++)
                #pragma unroll
                for (int r = 0; r < 4; r++)
                    B[mt*16 + q*4 + r][nt2*16 + li] =
                        fmaxf(h1[mt][nt2][r] + b1v[2*c1 + nt2], 0.f);
        WAVE_LDS_SYNC();   // this wave's writes visible to its own reads
        bfrag hah[4], hal[4];
        #pragma unroll
        for (int mt = 0; mt < 4; mt++)
            mk_frag(&B[mt*16 + li][q*8], hah[mt], hal[mt]);
        #pragma unroll
        for (int nt = 0; nt < 4; nt++) {
            int f = 4 + c1*4 + nt;
            bfrag bh = *(const bfrag*)(whi + (f*64 + lane)*8);
            bfrag bl = *(const bfrag*)(wlo + (f*64 + lane)*8);
            #pragma unroll
            for (int mt = 0; mt < 4; mt++) {
                cfrag a = h2acc[mt][nt];
                a = MFMA16(hal[mt], bh, a, 0, 0, 0);
                a = MFMA16(hah[mt], bl, a, 0, 0, 0);
                a = MFMA16(hah[mt], bh, a, 0, 0, 0);
                h2acc[mt][nt] = a;
            }
        }
    }

    cfrag oacc[4][2];
    #pragma unroll
    for (int mt = 0; mt < 4; mt++)
        #pragma unroll
        for (int nt = 0; nt < 2; nt++) oacc[mt][nt] = zc;

    #pragma unroll
    for (int c2 = 0; c2 < 2; c2++) {
        WAVE_LDS_SYNC();
        #pragma unroll
        for (int mt = 0; mt < 4; mt++)
            #pragma unroll
            for (int nt2 = 0; nt2 < 2; nt2++)
                #pragma unroll
                for (int r = 0; r < 4; r++)
                    B[mt*16 + q*4 + r][nt2*16 + li] =
                        fmaxf(h2acc[mt][2*c2 + nt2][r] + b2v[2*c2 + nt2], 0.f);
        WAVE_LDS_SYNC();
        bfrag hah[4], hal[4];
        #pragma unroll
        for (int mt = 0; mt < 4; mt++)
            mk_frag(&B[mt*16 + li][q*8], hah[mt], hal[mt]);
        #pragma unroll
        for (int nt = 0; nt < 2; nt++) {
            int f = 12 + c2*2 + nt;
            bfrag bh = *(const bfrag*)(whi + (f*64 + lane)*8);
            bfrag bl = *(const bfrag*)(wlo + (f*64 + lane)*8);
            #pragma unroll
            for (int mt = 0; mt < 4; mt++) {
                cfrag a = oacc[mt][nt];
                a = MFMA16(hal[mt], bh, a, 0, 0, 0);
                a = MFMA16(hah[mt], bl, a, 0, 0, 0);
                a = MFMA16(hah[mt], bh, a, 0, 0, 0);
                oacc[mt][nt] = a;
            }
        }
    }

    // O (C-layout) -> LDS -> per-lane (lane = its own sample row)
    WAVE_LDS_SYNC();
    #pragma unroll
    for (int mt = 0; mt < 4; mt++)
        #pragma unroll
        for (int nt = 0; nt < 2; nt++) {
            int ch = nt*16 + li;
            if (ch < 17) {
                #pragma unroll
                for (int r = 0; r < 4; r++)
                    B[mt*16 + q*4 + r][ch] = oacc[mt][nt][r] + b3v[nt];
            }
        }
    WAVE_LDS_SYNC();
    float4 o0 = *(float4*)&B[lane][0];
    float4 o1 = *(float4*)&B[lane][4];
    float4 o2 = *(float4*)&B[lane][8];
    float4 o3 = *(float4*)&B[lane][12];
    float o16 = B[lane][16];

    float density = fmaxf(o0.x, 0.f);
    float orgb[16] = {o0.y, o0.z, o0.w, o1.x, o1.y, o1.z, o1.w, o2.x,
                      o2.y, o2.z, o2.w, o3.x, o3.y, o3.z, o3.w, o16};

    // feats re-read from L2-hot xbuf (saves 16 live VGPRs across the MLP)
    float4 fx0 = *(const float4*)(X + lane * NC + 0);
    float4 fx1 = *(const float4*)(X + lane * NC + 4);
    float4 fx2 = *(const float4*)(X + lane * NC + 8);
    float4 fx3 = *(const float4*)(X + lane * NC + 12);
    float feats[16] = {fx0.x, fx0.y, fx0.z, fx0.w, fx1.x, fx1.y, fx1.z, fx1.w,
                       fx2.x, fx2.y, fx2.z, fx2.w, fx3.x, fx3.y, fx3.z, fx3.w};

    // ---- per-ray compositing ----
    float tv = znear + (zfar - znear) * ((float)lane / (float)(SPR - 1));
    float tn = znear + (zfar - znear) * ((float)(lane + 1) / (float)(SPR - 1));
    float delta = (lane < SPR - 1) ? (tn - tv) : 1e10f;
    float sigdel = density * delta;
    float alpha = 1.f - expf(-sigdel);
    float csum = sigdel;
    #pragma unroll
    for (int off = 1; off < 64; off <<= 1) {
        float nb = __shfl_up(csum, off, 64);
        if (lane >= off) csum += nb;
    }
    float wray = alpha * expf(-csum);

    #pragma unroll
    for (int c = 0; c < NC; c++) {
        float val = wray * (feats[c] + orgb[c]);
        #pragma unroll
        for (int off = 32; off >= 1; off >>= 1)
            val += __shfl_down(val, off, 64);
        if (lane == 0)
            rhalf[((b * NC + c) * HWH + py) * HWH + px] = val;
    }
}

// ---------------------------------------------------------------------------
// Scalar fallback (R6-proven) — only if ws too small.
// ---------------------------------------------------------------------------
__device__ __forceinline__ void mlp_and_composite(
    const float feats[NC], int lane, int b, int py, int px,
    float tv, float znear, float zfar,
    const float* __restrict__ W1, const float* __restrict__ B1,
    const float* __restrict__ W2, const float* __restrict__ B2,
    const float* __restrict__ W3, const float* __restrict__ B3,
    float* __restrict__ rhalf)
{
    float outa[17];
    #pragma unroll
    for (int c = 0; c < 17; c++) outa[c] = B3[c];
    for (int kc = 0; kc < 4; kc++) {
        float h2c[16];
        #pragma unroll
        for (int k = 0; k < 16; k++) h2c[k] = B2[kc * 16 + k];
        #pragma unroll 4
        for (int j = 0; j < 64; j++) {
            float a = B1[j];
            #pragma unroll
            for (int i = 0; i < NC; i++) a += feats[i] * W1[i * 64 + j];
            a = fmaxf(a, 0.f);
            const float* w2p = W2 + j * 64 + kc * 16;
            #pragma unroll
            for (int k = 0; k < 16; k++) h2c[k] += a * w2p[k];
        }
        #pragma unroll
        for (int k = 0; k < 16; k++) {
            float hv = fmaxf(h2c[k], 0.f);
            const float* w3p = W3 + (kc * 16 + k) * 17;
            #pragma unroll
            for (int c = 0; c < 17; c++) outa[c] += hv * w3p[c];
        }
    }
    float density = fmaxf(outa[0], 0.f);
    float tn = znear + (zfar - znear) * ((float)(lane + 1) / (float)(SPR - 1));
    float delta = (lane < SPR - 1) ? (tn - tv) : 1e10f;
    float sigdel = density * delta;
    float alpha = 1.f - expf(-sigdel);
    float csum = sigdel;
    #pragma unroll
    for (int off = 1; off < 64; off <<= 1) {
        float nb = __shfl_up(csum, off, 64);
        if (lane >= off) csum += nb;
    }
    float wray = alpha * expf(-csum);
    #pragma unroll
    for (int c = 0; c < NC; c++) {
        float val = wray * (feats[c] + outa[1 + c]);
        #pragma unroll
        for (int off = 32; off >= 1; off >>= 1)
            val += __shfl_down(val, off, 64);
        if (lane == 0)
            rhalf[((b * NC + c) * HWH + py) * HWH + px] = val;
    }
}

__global__ __launch_bounds__(256) void render_kernel(
    const float* __restrict__ enc,
    const float* __restrict__ ipose,
    const float* __restrict__ tpose,
    const float* __restrict__ focal_p,
    const float* __restrict__ znear_p,
    const float* __restrict__ zfar_p,
    const float* __restrict__ W1, const float* __restrict__ B1,
    const float* __restrict__ W2, const float* __restrict__ B2,
    const float* __restrict__ W3, const float* __restrict__ B3,
    float* __restrict__ rhalf)
{
    const int lane = threadIdx.x & 63;
    const int ray  = blockIdx.x * 4 + (threadIdx.x >> 6);
    const int px   = ray % HWH;
    const int py   = (ray / HWH) % HWH;
    const int b    = ray / (HWH * HWH);
    const int s    = b >> 2;
    const float focal = focal_p[0];
    const float znear = znear_p[0];
    const float zfar  = zfar_p[0];
    const float* P = tpose + b * 16;
    float ysc = ((py + 0.5f) / (float)HWH) * 2.f - 1.f;
    float xsc = ((px + 0.5f) / (float)HWH) * 2.f - 1.f;
    float dcx = xsc / focal, dcy = -ysc / focal, dcz = -1.f;
    float dirx = P[0]*dcx + P[1]*dcy + P[2]*dcz;
    float diry = P[4]*dcx + P[5]*dcy + P[6]*dcz;
    float dirz = P[8]*dcx + P[9]*dcy + P[10]*dcz;
    float tv  = znear + (zfar - znear) * ((float)lane / (float)(SPR - 1));
    float ptx = P[3] + tv * dirx, pty = P[7] + tv * diry, ptz = P[11] + tv * dirz;
    float feats[NC];
    #pragma unroll
    for (int c = 0; c < NC; c++) feats[c] = 0.f;
    const float minz = focal * znear, maxz = focal * zfar;
    for (int v = 0; v < NVIN; v++) {
        const float* E = ipose + (s * NVIN + v) * 16;
        float qx = ptx - E[3], qy = pty - E[7], qz = ptz - E[11];
        float lx = E[0]*qx + E[4]*qy + E[8]*qz;
        float ly = E[1]*qx + E[5]*qy + E[9]*qz;
        float lz = E[2]*qx + E[6]*qy + E[10]*qz;
        float zz = -lz;
        float u  = lx / zz * focal;
        float vv = ly / zz * focal;
        float wd = 2.f * (zz - minz) / (maxz - minz) - 1.f;
        float ix = ((u   + 1.f) * NW - 1.f) * 0.5f;
        float iy = ((-vv + 1.f) * NH - 1.f) * 0.5f;
        float iz = ((-wd + 1.f) * ND - 1.f) * 0.5f;
        float x0 = floorf(ix), y0 = floorf(iy), z0 = floorf(iz);
        float wgt[8]; int idx[8];
        #pragma unroll
        for (int k = 0; k < 8; k++) {
            float xc = x0 + (k & 1), yc = y0 + ((k >> 1) & 1), zc = z0 + (k >> 2);
            float wt = (1.f - fabsf(ix - xc)) * (1.f - fabsf(iy - yc)) * (1.f - fabsf(iz - zc));
            bool valid = (xc >= 0.f) && (xc < (float)NW) &&
                         (yc >= 0.f) && (yc < (float)NH) &&
                         (zc >= 0.f) && (zc < (float)ND);
            wgt[k] = valid ? wt : 0.f;
            int xi = min(max((int)xc, 0), NW - 1);
            int yi = min(max((int)yc, 0), NH - 1);
            int zi = min(max((int)zc, 0), ND - 1);
            idx[k] = (zi * NH + yi) * NW + xi;
        }
        const float* VB = enc + (size_t)(s * NVIN + v) * NC * DHW;
        #pragma unroll
        for (int c = 0; c < NC; c++) {
            const float* vc = VB + c * DHW;
            float acc = 0.f;
            #pragma unroll
            for (int k = 0; k < 8; k++) acc += wgt[k] * vc[idx[k]];
            feats[c] += acc;
        }
    }
    #pragma unroll
    for (int c = 0; c < NC; c++) feats[c] *= (1.f / 3.f);
    mlp_and_composite(feats, lane, b, py, px, tv, znear, zfar,
                      W1, B1, W2, B2, W3, B3, rhalf);
}

// 2x bilinear upsample, align_corners=True.
__global__ __launch_bounds__(256) void upsample_kernel(
    const float* __restrict__ in, float* __restrict__ out)
{
    int tid = blockIdx.x * 256 + threadIdx.x;
    int ox = tid % NW;
    int oy = (tid / NW) % NH;
    int c  = (tid / (NW * NH)) % NC;
    int b  = tid / (NW * NH * NC);
    const float sc = (float)((HWH - 1) / (double)(NH - 1)); // 47/95
    float pyf = oy * sc;
    float pxf = ox * sc;
    int y0 = (int)floorf(pyf); int y1 = min(y0 + 1, HWH - 1); float fy = pyf - y0;
    int x0 = (int)floorf(pxf); int x1 = min(x0 + 1, HWH - 1); float fx = pxf - x0;
    const float* src = in + (b * NC + c) * HWH * HWH;
    float v00 = src[y0 * HWH + x0], v01 = src[y0 * HWH + x1];
    float v10 = src[y1 * HWH + x0], v11 = src[y1 * HWH + x1];
    float gl = v00 * (1.f - fy) + v10 * fy;
    float gr = v01 * (1.f - fy) + v11 * fy;
    out[tid] = gl * (1.f - fx) + gr * fx;
}

extern "C" void kernel_launch(void* const* d_in, const int* in_sizes, int n_in,
                              void* d_out, int out_size, void* d_ws, size_t ws_size,
                              hipStream_t stream) {
    const float* enc   = (const float*)d_in[0];
    const float* ipose = (const float*)d_in[1];
    const float* tpose = (const float*)d_in[2];
    const float* focal = (const float*)d_in[3];
    const float* znear = (const float*)d_in[4];
    const float* zfar  = (const float*)d_in[5];
    const float* W1 = (const float*)d_in[7];
    const float* B1 = (const float*)d_in[8];
    const float* W2 = (const float*)d_in[9];
    const float* B2 = (const float*)d_in[10];
    const float* W3 = (const float*)d_in[11];
    const float* B3 = (const float*)d_in[12];

    float* out = (float*)d_out;
    const int nrays = NRAYS;                             // 18432
    const int nout  = NS * NVT * NC * NH * NW;           // 1179648
    const size_t enc_t_bytes = (size_t)NS * NVIN * NC * DHW * 4;   // 226.5 MB
    const size_t rhalf_bytes = (size_t)nrays * NC * 4;             // 1.18 MB
    const size_t wfrag_bytes = 16 * 64 * 8 * sizeof(short);        // 16 KB
    const size_t xbuf_bytes  = (size_t)NSAMP * NC * 4;             // 75.5 MB

    if (ws_size >= enc_t_bytes + rhalf_bytes + 2 * wfrag_bytes + xbuf_bytes) {
        char* base = (char*)d_ws;
        float* enc_t = (float*)base;                      base += enc_t_bytes;
        float* rhalf = (float*)base;                      base += rhalf_bytes;
        short* whi   = (short*)base;                      base += wfrag_bytes;
        short* wlo   = (short*)base;                      base += wfrag_bytes;
        float* xbuf  = (float*)base;

        wprep_kernel<<<4, 256, 0, stream>>>(W1, W2, W3, whi, wlo);
        transpose_kernel<<<NS * NVIN * NTILE, 256, 0, stream>>>(enc, enc_t);
        gather_kernel<<<nrays, 256, 0, stream>>>(
            enc_t, ipose, tpose, focal, znear, zfar, xbuf);
        mlp_kernel<<<nrays / 4, 256, 0, stream>>>(
            xbuf, znear, zfar, whi, wlo, B1, B2, B3, rhalf);
        upsample_kernel<<<nout / 256, 256, 0, stream>>>(rhalf, out);
    } else {
        float* rhalf = (float*)d_ws;
        render_kernel<<<nrays / 4, 256, 0, stream>>>(
            enc, ipose, tpose, focal, znear, zfar,
            W1, B1, W2, B2, W3, B3, rhalf);
        upsample_kernel<<<nout / 256, 256, 0, stream>>>(rhalf, out);
    }
}

// Round 5
// 607.357 us; speedup vs baseline: 1.0155x; 1.0155x over previous
//
#include <hip/hip_runtime.h>
#include <hip/hip_bf16.h>
#include <math.h>

// Problem constants (fixed by setup_inputs)
#define NS   2
#define NVIN 3
#define NVT  4
#define NC   16
#define ND   64
#define NH   96
#define NW   96
#define HWH  48          // half res h=w
#define SPR  64
#define DHW  (ND*NH*NW)  // 589824
#define NTILE (DHW / 64) // 9216 — NOT a power of two
#define NSAMP (NS*NVT*HWH*HWH*SPR)   // 1179648 samples
#define NRAYS (NS*NVT*HWH*HWH)       // 18432 (% 8 == 0)

typedef __attribute__((ext_vector_type(8))) short bfrag;   // 8 bf16 (4 VGPR)
typedef __attribute__((ext_vector_type(4))) float cfrag;   // 4 fp32 acc

#define MFMA16 __builtin_amdgcn_mfma_f32_16x16x32_bf16

// Wave-local LDS ordering: each wave's sbuf slice is private, so a block
// barrier is never needed — only completion/ordering of THIS wave's DS ops.
// (R1 lesson: do NOT fuse the latency-bound gather into the MLP kernel.)
#define WAVE_LDS_SYNC() asm volatile("s_waitcnt lgkmcnt(0)" ::: "memory")

__device__ __forceinline__ short f2bf(float x) {
    union { __hip_bfloat16 b; short s; } cv;
    cv.b = __float2bfloat16(x);
    return cv.s;
}
__device__ __forceinline__ float bf2f(short s) {
    union { unsigned int u; float f; } cv;
    cv.u = ((unsigned int)(unsigned short)s) << 16;
    return cv.f;
}

// Build hi/lo bf16 A-fragment from 8 consecutive fp32 (LDS or global).
// Verified layout (m120): A[m=lane&15][k=(lane>>4)*8+j], j=0..7.
__device__ __forceinline__ void mk_frag(const float* p, bfrag& ah, bfrag& al) {
    float4 v0 = *(const float4*)p;
    float4 v1 = *(const float4*)(p + 4);
    float e[8] = {v0.x, v0.y, v0.z, v0.w, v1.x, v1.y, v1.z, v1.w};
    #pragma unroll
    for (int j = 0; j < 8; j++) {
        short h = f2bf(e[j]);
        ah[j] = h;
        al[j] = f2bf(e[j] - bf2f(h));
    }
}

// ---------------------------------------------------------------------------
// Weight-fragment prep (R7-verified): split W1/W2/W3 into bf16 hi/lo,
// fragment-linear so each lane loads its B-fragment with one dwordx4.
// ---------------------------------------------------------------------------
__global__ __launch_bounds__(256) void wprep_kernel(
    const float* __restrict__ W1, const float* __restrict__ W2,
    const float* __restrict__ W3, short* __restrict__ whi, short* __restrict__ wlo)
{
    int t = blockIdx.x * 256 + threadIdx.x;   // 1024 total
    int f = t >> 6, L = t & 63;
    int q = L >> 4, li = L & 15;
    #pragma unroll
    for (int j = 0; j < 8; j++) {
        int kloc = q * 8 + j;                 // 0..31
        float w = 0.f;
        if (f < 4) {
            int n = f * 16 + li, k = kloc;
            if (k < 16) w = W1[k * 64 + n];
        } else if (f < 12) {
            int kt = (f - 4) >> 2, nt = (f - 4) & 3;
            w = W2[(kt * 32 + kloc) * 64 + nt * 16 + li];
        } else {
            int kt = (f - 12) >> 1, nt = (f - 12) & 1;
            int n = nt * 16 + li;
            if (n < 17) w = W3[(kt * 32 + kloc) * 17 + n];
        }
        short h = f2bf(w);
        whi[(f * 64 + L) * 8 + j] = h;
        wlo[(f * 64 + L) * 8 + j] = f2bf(w - bf2f(h));
    }
}

// ---------------------------------------------------------------------------
// LDS-tiled transpose enc [6][16][DHW] -> enc_t [6][DHW][16].
// ---------------------------------------------------------------------------
__global__ __launch_bounds__(256) void transpose_kernel(
    const float* __restrict__ in, float* __restrict__ out)
{
    __shared__ float tile[NC][64 + 4];
    const int t   = threadIdx.x;
    const int blk = blockIdx.x;
    const int vox0 = (blk % NTILE) * 64;
    const int sv   = blk / NTILE;

    const int c  = t >> 4;
    const int vg = (t & 15) * 4;
    const float* src = in + ((size_t)sv * NC + c) * DHW + vox0 + vg;
    float4 v = *(const float4*)src;
    tile[c][vg + 0] = v.x; tile[c][vg + 1] = v.y;
    tile[c][vg + 2] = v.z; tile[c][vg + 3] = v.w;
    __syncthreads();

    const int ov = t >> 2;
    const int oc = (t & 3) * 4;
    float4 w = make_float4(tile[oc + 0][ov], tile[oc + 1][ov],
                           tile[oc + 2][ov], tile[oc + 3][ov]);
    float* dst = out + ((size_t)sv * DHW + vox0 + ov) * NC + oc;
    *(float4*)dst = w;
}

// ---------------------------------------------------------------------------
// Gather v4: 8 lanes per sample = (xbit, c4). The 8-lane group's two x-corner
// voxel lines are CONTIGUOUS 128 B (x is the fast axis of enc_t) -> pairs
// merge at the TCC, halving L2 line requests. Each iteration issues its 12
// loads (3 views x 4 zy-corners) as one explicit batch into a live array
// BEFORE consumption -> ~12 in-flight vmem/wave instead of ~2 (R3 evidence:
// VALU cut + FETCH cut both produced zero time delta => latency/request
// bound, not VALU/BW bound). x0/x1 partials merge via one shfl_xor(4).
// Weights keep R3's exact per-axis factorization and association.
// ---------------------------------------------------------------------------
__global__ __launch_bounds__(256) void gather_kernel(
    const float* __restrict__ enc_t,
    const float* __restrict__ ipose,
    const float* __restrict__ tpose,
    const float* __restrict__ focal_p,
    const float* __restrict__ znear_p,
    const float* __restrict__ zfar_p,
    float* __restrict__ xbuf)
{
    // one block == one ray; XCD-chunked swizzle (R3, kept: halved FETCH)
    const int ray  = (blockIdx.x & 7) * (NRAYS >> 3) + (blockIdx.x >> 3);
    const int lane = threadIdx.x & 63;
    const int wv   = threadIdx.x >> 6;
    const int c4   = lane & 3;
    const int xbit = (lane >> 2) & 1;
    const int ds   = lane >> 3;          // 0..7: sample slot within wave
    const int px   = ray % HWH;
    const int py   = (ray / HWH) % HWH;
    const int b    = ray / (HWH * HWH);
    const int s    = b >> 2;

    const float focal = focal_p[0];
    const float znear = znear_p[0];
    const float zfar  = zfar_p[0];

    const float* P = tpose + b * 16;
    float ysc = ((py + 0.5f) / (float)HWH) * 2.f - 1.f;
    float xsc = ((px + 0.5f) / (float)HWH) * 2.f - 1.f;
    float dcx = xsc / focal, dcy = -ysc / focal, dcz = -1.f;
    float dirx = P[0]*dcx + P[1]*dcy + P[2]*dcz;
    float diry = P[4]*dcx + P[5]*dcy + P[6]*dcz;
    float dirz = P[8]*dcx + P[9]*dcy + P[10]*dcz;

    // Per-view hoist (R0-verified algebra): local = R^T(o-t) + tv * R^T dir.
    // Block-uniform -> lands in SGPRs.
    float lox[NVIN], loy[NVIN], loz[NVIN];
    float ldx[NVIN], ldy[NVIN], ldz[NVIN];
    #pragma unroll
    for (int v = 0; v < NVIN; v++) {
        const float* E = ipose + (s * NVIN + v) * 16;
        float qx = P[3] - E[3], qy = P[7] - E[7], qz = P[11] - E[11];
        lox[v] = E[0]*qx + E[4]*qy + E[8]*qz;
        loy[v] = E[1]*qx + E[5]*qy + E[9]*qz;
        loz[v] = E[2]*qx + E[6]*qy + E[10]*qz;
        ldx[v] = E[0]*dirx + E[4]*diry + E[8]*dirz;
        ldy[v] = E[1]*dirx + E[5]*diry + E[9]*dirz;
        ldz[v] = E[2]*dirx + E[6]*diry + E[10]*dirz;
    }

    const float minz = focal * znear, maxz = focal * zfar;
    const float inv3 = 1.f / 3.f;

    #pragma unroll 1
    for (int iter = 0; iter < 2; iter++) {
        const int d = wv * 8 + ds + iter * 32;   // 0..63
        float tv = znear + (zfar - znear) * ((float)d / (float)(SPR - 1));

        float wgt[12];
        int   off[12];
        #pragma unroll
        for (int v = 0; v < NVIN; v++) {
            float lx = lox[v] + tv * ldx[v];
            float ly = loy[v] + tv * ldy[v];
            float lz = loz[v] + tv * ldz[v];
            float zz = -lz;
            float u  = lx / zz * focal;
            float vv = ly / zz * focal;
            float wd = 2.f * (zz - minz) / (maxz - minz) - 1.f;
            float ix = ((u   + 1.f) * NW - 1.f) * 0.5f;
            float iy = ((-vv + 1.f) * NH - 1.f) * 0.5f;
            float iz = ((-wd + 1.f) * ND - 1.f) * 0.5f;
            float x0 = floorf(ix), y0 = floorf(iy), z0 = floorf(iz);
            float x1 = x0 + 1.f,   y1 = y0 + 1.f,   z1 = z0 + 1.f;

            float wxa0 = 1.f - fabsf(ix - x0), wxa1 = 1.f - fabsf(ix - x1);
            float wya0 = 1.f - fabsf(iy - y0), wya1 = 1.f - fabsf(iy - y1);
            float wza0 = 1.f - fabsf(iz - z0), wza1 = 1.f - fabsf(iz - z1);
            wxa0 = (x0 >= 0.f && x0 < (float)NW) ? wxa0 : 0.f;
            wxa1 = (x1 >= 0.f && x1 < (float)NW) ? wxa1 : 0.f;
            wya0 = (y0 >= 0.f && y0 < (float)NH) ? wya0 : 0.f;
            wya1 = (y1 >= 0.f && y1 < (float)NH) ? wya1 : 0.f;
            wza0 = (z0 >= 0.f && z0 < (float)ND) ? wza0 : 0.f;
            wza1 = (z1 >= 0.f && z1 < (float)ND) ? wza1 : 0.f;

            int xi0 = min(max((int)x0, 0), NW - 1), xi1 = min(max((int)x1, 0), NW - 1);
            int yi0 = min(max((int)y0, 0), NH - 1), yi1 = min(max((int)y1, 0), NH - 1);
            int zi0 = min(max((int)z0, 0), ND - 1), zi1 = min(max((int)z1, 0), ND - 1);
            int o00 = (zi0 * NH + yi0) * NW, o01 = (zi0 * NH + yi1) * NW;
            int o10 = (zi1 * NH + yi0) * NW, o11 = (zi1 * NH + yi1) * NW;

            // this lane's x-side
            float wxl = xbit ? wxa1 : wxa0;
            int   xil = xbit ? xi1  : xi0;

            wgt[v*4 + 0] = (wxl * wya0) * wza0;  off[v*4 + 0] = (o00 + xil) * NC + c4 * 4;
            wgt[v*4 + 1] = (wxl * wya1) * wza0;  off[v*4 + 1] = (o01 + xil) * NC + c4 * 4;
            wgt[v*4 + 2] = (wxl * wya0) * wza1;  off[v*4 + 2] = (o10 + xil) * NC + c4 * 4;
            wgt[v*4 + 3] = (wxl * wya1) * wza1;  off[v*4 + 3] = (o11 + xil) * NC + c4 * 4;
        }

        // batch-issue all 12 loads (live array forces them in flight together)
        float4 av[12];
        #pragma unroll
        for (int j = 0; j < 12; j++) {
            const float* VB = enc_t + (size_t)(s * NVIN + (j >> 2)) * DHW * NC;
            av[j] = *(const float4*)(VB + off[j]);
        }

        float f0 = 0.f, f1 = 0.f, f2 = 0.f, f3 = 0.f;
        #pragma unroll
        for (int j = 0; j < 12; j++) {
            f0 += wgt[j] * av[j].x; f1 += wgt[j] * av[j].y;
            f2 += wgt[j] * av[j].z; f3 += wgt[j] * av[j].w;
        }
        // merge x0/x1 halves (partner lane differs only in xbit)
        f0 += __shfl_xor(f0, 4, 64);
        f1 += __shfl_xor(f1, 4, 64);
        f2 += __shfl_xor(f2, 4, 64);
        f3 += __shfl_xor(f3, 4, 64);

        if (!xbit)
            ((float4*)xbuf)[(ray * 64 + d) * 4 + c4] =
                make_float4(f0 * inv3, f1 * inv3, f2 * inv3, f3 * inv3);
    }
}

// ---------------------------------------------------------------------------
// MFMA MLP + composite (R7-verified pipeline, A-frags from global xbuf).
// One wave per ray; block = 4 rays. bf16 hi/lo 3-product = fp32-accurate.
// R2: sbuf slices are per-wave, so every __syncthreads() is replaced by a
// wave-local lgkmcnt(0) — zero cross-wave barriers (verified win).
// ---------------------------------------------------------------------------
__global__ __launch_bounds__(256) void mlp_kernel(
    const float* __restrict__ xbuf,
    const float* __restrict__ znear_p,
    const float* __restrict__ zfar_p,
    const short* __restrict__ whi, const short* __restrict__ wlo,
    const float* __restrict__ B1, const float* __restrict__ B2,
    const float* __restrict__ B3,
    float* __restrict__ rhalf)
{
    const int lane = threadIdx.x & 63;
    const int ray  = blockIdx.x * 4 + (threadIdx.x >> 6);
    const int px   = ray % HWH;
    const int py   = (ray / HWH) % HWH;
    const int b    = ray / (HWH * HWH);

    const float znear = znear_p[0];
    const float zfar  = zfar_p[0];

    __shared__ float sbuf[4][64][36];   // per-wave 64x36 staging (36.9 KB)
    float (*B)[36] = sbuf[threadIdx.x >> 6];
    const int li = lane & 15, q = lane >> 4;
    const float* X = xbuf + (size_t)ray * 64 * NC;   // this ray's 64x16 rows

    float b1v[4], b2v[4], b3v[2];
    #pragma unroll
    for (int nt = 0; nt < 4; nt++) { b1v[nt] = B1[nt*16 + li]; b2v[nt] = B2[nt*16 + li]; }
    b3v[0] = B3[li];
    b3v[1] = (li == 0) ? B3[16] : 0.f;

    // layer-1 A-frags straight from global X (K=16; q>=2 lanes are zero pad)
    bfrag xah[4], xal[4];
    bfrag zb = {0,0,0,0,0,0,0,0};
    #pragma unroll
    for (int mt = 0; mt < 4; mt++) {
        if (q < 2) mk_frag(X + (mt*16 + li) * NC + q * 8, xah[mt], xal[mt]);
        else { xah[mt] = zb; xal[mt] = zb; }
    }

    cfrag zc = {0.f, 0.f, 0.f, 0.f};
    cfrag h2acc[4][4];
    #pragma unroll
    for (int mt = 0; mt < 4; mt++)
        #pragma unroll
        for (int nt = 0; nt < 4; nt++) h2acc[mt][nt] = zc;

    #pragma unroll
    for (int c1 = 0; c1 < 2; c1++) {
        cfrag h1[4][2];
        #pragma unroll
        for (int nt2 = 0; nt2 < 2; nt2++) {
            int f = 2*c1 + nt2;
            bfrag bh = *(const bfrag*)(whi + (f*64 + lane)*8);
            bfrag bl = *(const bfrag*)(wlo + (f*64 + lane)*8);
            #pragma unroll
            for (int mt = 0; mt < 4; mt++) {
                cfrag a = zc;
                a = MFMA16(xal[mt], bh, a, 0, 0, 0);
                a = MFMA16(xah[mt], bl, a, 0, 0, 0);
                a = MFMA16(xah[mt], bh, a, 0, 0, 0);
                h1[mt][nt2] = a;
            }
        }
        WAVE_LDS_SYNC();   // prior iter's staging reads ordered before writes
        #pragma unroll
        for (int mt = 0; mt < 4; mt++)
            #pragma unroll
            for (int nt2 = 0; nt2 < 2; nt2++)
                #pragma unroll
                for (int r = 0; r < 4; r++)
                    B[mt*16 + q*4 + r][nt2*16 + li] =
                        fmaxf(h1[mt][nt2][r] + b1v[2*c1 + nt2], 0.f);
        WAVE_LDS_SYNC();   // this wave's writes visible to its own reads
        bfrag hah[4], hal[4];
        #pragma unroll
        for (int mt = 0; mt < 4; mt++)
            mk_frag(&B[mt*16 + li][q*8], hah[mt], hal[mt]);
        #pragma unroll
        for (int nt = 0; nt < 4; nt++) {
            int f = 4 + c1*4 + nt;
            bfrag bh = *(const bfrag*)(whi + (f*64 + lane)*8);
            bfrag bl = *(const bfrag*)(wlo + (f*64 + lane)*8);
            #pragma unroll
            for (int mt = 0; mt < 4; mt++) {
                cfrag a = h2acc[mt][nt];
                a = MFMA16(hal[mt], bh, a, 0, 0, 0);
                a = MFMA16(hah[mt], bl, a, 0, 0, 0);
                a = MFMA16(hah[mt], bh, a, 0, 0, 0);
                h2acc[mt][nt] = a;
            }
        }
    }

    cfrag oacc[4][2];
    #pragma unroll
    for (int mt = 0; mt < 4; mt++)
        #pragma unroll
        for (int nt = 0; nt < 2; nt++) oacc[mt][nt] = zc;

    #pragma unroll
    for (int c2 = 0; c2 < 2; c2++) {
        WAVE_LDS_SYNC();
        #pragma unroll
        for (int mt = 0; mt < 4; mt++)
            #pragma unroll
            for (int nt2 = 0; nt2 < 2; nt2++)
                #pragma unroll
                for (int r = 0; r < 4; r++)
                    B[mt*16 + q*4 + r][nt2*16 + li] =
                        fmaxf(h2acc[mt][2*c2 + nt2][r] + b2v[2*c2 + nt2], 0.f);
        WAVE_LDS_SYNC();
        bfrag hah[4], hal[4];
        #pragma unroll
        for (int mt = 0; mt < 4; mt++)
            mk_frag(&B[mt*16 + li][q*8], hah[mt], hal[mt]);
        #pragma unroll
        for (int nt = 0; nt < 2; nt++) {
            int f = 12 + c2*2 + nt;
            bfrag bh = *(const bfrag*)(whi + (f*64 + lane)*8);
            bfrag bl = *(const bfrag*)(wlo + (f*64 + lane)*8);
            #pragma unroll
            for (int mt = 0; mt < 4; mt++) {
                cfrag a = oacc[mt][nt];
                a = MFMA16(hal[mt], bh, a, 0, 0, 0);
                a = MFMA16(hah[mt], bl, a, 0, 0, 0);
                a = MFMA16(hah[mt], bh, a, 0, 0, 0);
                oacc[mt][nt] = a;
            }
        }
    }

    // O (C-layout) -> LDS -> per-lane (lane = its own sample row)
    WAVE_LDS_SYNC();
    #pragma unroll
    for (int mt = 0; mt < 4; mt++)
        #pragma unroll
        for (int nt = 0; nt < 2; nt++) {
            int ch = nt*16 + li;
            if (ch < 17) {
                #pragma unroll
                for (int r = 0; r < 4; r++)
                    B[mt*16 + q*4 + r][ch] = oacc[mt][nt][r] + b3v[nt];
            }
        }
    WAVE_LDS_SYNC();
    float4 o0 = *(float4*)&B[lane][0];
    float4 o1 = *(float4*)&B[lane][4];
    float4 o2 = *(float4*)&B[lane][8];
    float4 o3 = *(float4*)&B[lane][12];
    float o16 = B[lane][16];

    float density = fmaxf(o0.x, 0.f);
    float orgb[16] = {o0.y, o0.z, o0.w, o1.x, o1.y, o1.z, o1.w, o2.x,
                      o2.y, o2.z, o2.w, o3.x, o3.y, o3.z, o3.w, o16};

    // feats re-read from L2-hot xbuf (saves 16 live VGPRs across the MLP)
    float4 fx0 = *(const float4*)(X + lane * NC + 0);
    float4 fx1 = *(const float4*)(X + lane * NC + 4);
    float4 fx2 = *(const float4*)(X + lane * NC + 8);
    float4 fx3 = *(const float4*)(X + lane * NC + 12);
    float feats[16] = {fx0.x, fx0.y, fx0.z, fx0.w, fx1.x, fx1.y, fx1.z, fx1.w,
                       fx2.x, fx2.y, fx2.z, fx2.w, fx3.x, fx3.y, fx3.z, fx3.w};

    // ---- per-ray compositing ----
    float tv = znear + (zfar - znear) * ((float)lane / (float)(SPR - 1));
    float tn = znear + (zfar - znear) * ((float)(lane + 1) / (float)(SPR - 1));
    float delta = (lane < SPR - 1) ? (tn - tv) : 1e10f;
    float sigdel = density * delta;
    float alpha = 1.f - expf(-sigdel);
    float csum = sigdel;
    #pragma unroll
    for (int off = 1; off < 64; off <<= 1) {
        float nb = __shfl_up(csum, off, 64);
        if (lane >= off) csum += nb;
    }
    float wray = alpha * expf(-csum);

    #pragma unroll
    for (int c = 0; c < NC; c++) {
        float val = wray * (feats[c] + orgb[c]);
        #pragma unroll
        for (int off = 32; off >= 1; off >>= 1)
            val += __shfl_down(val, off, 64);
        if (lane == 0)
            rhalf[((b * NC + c) * HWH + py) * HWH + px] = val;
    }
}

// ---------------------------------------------------------------------------
// Scalar fallback (R6-proven) — only if ws too small.
// ---------------------------------------------------------------------------
__device__ __forceinline__ void mlp_and_composite(
    const float feats[NC], int lane, int b, int py, int px,
    float tv, float znear, float zfar,
    const float* __restrict__ W1, const float* __restrict__ B1,
    const float* __restrict__ W2, const float* __restrict__ B2,
    const float* __restrict__ W3, const float* __restrict__ B3,
    float* __restrict__ rhalf)
{
    float outa[17];
    #pragma unroll
    for (int c = 0; c < 17; c++) outa[c] = B3[c];
    for (int kc = 0; kc < 4; kc++) {
        float h2c[16];
        #pragma unroll
        for (int k = 0; k < 16; k++) h2c[k] = B2[kc * 16 + k];
        #pragma unroll 4
        for (int j = 0; j < 64; j++) {
            float a = B1[j];
            #pragma unroll
            for (int i = 0; i < NC; i++) a += feats[i] * W1[i * 64 + j];
            a = fmaxf(a, 0.f);
            const float* w2p = W2 + j * 64 + kc * 16;
            #pragma unroll
            for (int k = 0; k < 16; k++) h2c[k] += a * w2p[k];
        }
        #pragma unroll
        for (int k = 0; k < 16; k++) {
            float hv = fmaxf(h2c[k], 0.f);
            const float* w3p = W3 + (kc * 16 + k) * 17;
            #pragma unroll
            for (int c = 0; c < 17; c++) outa[c] += hv * w3p[c];
        }
    }
    float density = fmaxf(outa[0], 0.f);
    float tn = znear + (zfar - znear) * ((float)(lane + 1) / (float)(SPR - 1));
    float delta = (lane < SPR - 1) ? (tn - tv) : 1e10f;
    float sigdel = density * delta;
    float alpha = 1.f - expf(-sigdel);
    float csum = sigdel;
    #pragma unroll
    for (int off = 1; off < 64; off <<= 1) {
        float nb = __shfl_up(csum, off, 64);
        if (lane >= off) csum += nb;
    }
    float wray = alpha * expf(-csum);
    #pragma unroll
    for (int c = 0; c < NC; c++) {
        float val = wray * (feats[c] + outa[1 + c]);
        #pragma unroll
        for (int off = 32; off >= 1; off >>= 1)
            val += __shfl_down(val, off, 64);
        if (lane == 0)
            rhalf[((b * NC + c) * HWH + py) * HWH + px] = val;
    }
}

__global__ __launch_bounds__(256) void render_kernel(
    const float* __restrict__ enc,
    const float* __restrict__ ipose,
    const float* __restrict__ tpose,
    const float* __restrict__ focal_p,
    const float* __restrict__ znear_p,
    const float* __restrict__ zfar_p,
    const float* __restrict__ W1, const float* __restrict__ B1,
    const float* __restrict__ W2, const float* __restrict__ B2,
    const float* __restrict__ W3, const float* __restrict__ B3,
    float* __restrict__ rhalf)
{
    const int lane = threadIdx.x & 63;
    const int ray  = blockIdx.x * 4 + (threadIdx.x >> 6);
    const int px   = ray % HWH;
    const int py   = (ray / HWH) % HWH;
    const int b    = ray / (HWH * HWH);
    const int s    = b >> 2;
    const float focal = focal_p[0];
    const float znear = znear_p[0];
    const float zfar  = zfar_p[0];
    const float* P = tpose + b * 16;
    float ysc = ((py + 0.5f) / (float)HWH) * 2.f - 1.f;
    float xsc = ((px + 0.5f) / (float)HWH) * 2.f - 1.f;
    float dcx = xsc / focal, dcy = -ysc / focal, dcz = -1.f;
    float dirx = P[0]*dcx + P[1]*dcy + P[2]*dcz;
    float diry = P[4]*dcx + P[5]*dcy + P[6]*dcz;
    float dirz = P[8]*dcx + P[9]*dcy + P[10]*dcz;
    float tv  = znear + (zfar - znear) * ((float)lane / (float)(SPR - 1));
    float ptx = P[3] + tv * dirx, pty = P[7] + tv * diry, ptz = P[11] + tv * dirz;
    float feats[NC];
    #pragma unroll
    for (int c = 0; c < NC; c++) feats[c] = 0.f;
    const float minz = focal * znear, maxz = focal * zfar;
    for (int v = 0; v < NVIN; v++) {
        const float* E = ipose + (s * NVIN + v) * 16;
        float qx = ptx - E[3], qy = pty - E[7], qz = ptz - E[11];
        float lx = E[0]*qx + E[4]*qy + E[8]*qz;
        float ly = E[1]*qx + E[5]*qy + E[9]*qz;
        float lz = E[2]*qx + E[6]*qy + E[10]*qz;
        float zz = -lz;
        float u  = lx / zz * focal;
        float vv = ly / zz * focal;
        float wd = 2.f * (zz - minz) / (maxz - minz) - 1.f;
        float ix = ((u   + 1.f) * NW - 1.f) * 0.5f;
        float iy = ((-vv + 1.f) * NH - 1.f) * 0.5f;
        float iz = ((-wd + 1.f) * ND - 1.f) * 0.5f;
        float x0 = floorf(ix), y0 = floorf(iy), z0 = floorf(iz);
        float wgt[8]; int idx[8];
        #pragma unroll
        for (int k = 0; k < 8; k++) {
            float xc = x0 + (k & 1), yc = y0 + ((k >> 1) & 1), zc = z0 + (k >> 2);
            float wt = (1.f - fabsf(ix - xc)) * (1.f - fabsf(iy - yc)) * (1.f - fabsf(iz - zc));
            bool valid = (xc >= 0.f) && (xc < (float)NW) &&
                         (yc >= 0.f) && (yc < (float)NH) &&
                         (zc >= 0.f) && (zc < (float)ND);
            wgt[k] = valid ? wt : 0.f;
            int xi = min(max((int)xc, 0), NW - 1);
            int yi = min(max((int)yc, 0), NH - 1);
            int zi = min(max((int)zc, 0), ND - 1);
            idx[k] = (zi * NH + yi) * NW + xi;
        }
        const float* VB = enc + (size_t)(s * NVIN + v) * NC * DHW;
        #pragma unroll
        for (int c = 0; c < NC; c++) {
            const float* vc = VB + c * DHW;
            float acc = 0.f;
            #pragma unroll
            for (int k = 0; k < 8; k++) acc += wgt[k] * vc[idx[k]];
            feats[c] += acc;
        }
    }
    #pragma unroll
    for (int c = 0; c < NC; c++) feats[c] *= (1.f / 3.f);
    mlp_and_composite(feats, lane, b, py, px, tv, znear, zfar,
                      W1, B1, W2, B2, W3, B3, rhalf);
}

// 2x bilinear upsample, align_corners=True.
__global__ __launch_bounds__(256) void upsample_kernel(
    const float* __restrict__ in, float* __restrict__ out)
{
    int tid = blockIdx.x * 256 + threadIdx.x;
    int ox = tid % NW;
    int oy = (tid / NW) % NH;
    int c  = (tid / (NW * NH)) % NC;
    int b  = tid / (NW * NH * NC);
    const float sc = (float)((HWH - 1) / (double)(NH - 1)); // 47/95
    float pyf = oy * sc;
    float pxf = ox * sc;
    int y0 = (int)floorf(pyf); int y1 = min(y0 + 1, HWH - 1); float fy = pyf - y0;
    int x0 = (int)floorf(pxf); int x1 = min(x0 + 1, HWH - 1); float fx = pxf - x0;
    const float* src = in + (b * NC + c) * HWH * HWH;
    float v00 = src[y0 * HWH + x0], v01 = src[y0 * HWH + x1];
    float v10 = src[y1 * HWH + x0], v11 = src[y1 * HWH + x1];
    float gl = v00 * (1.f - fy) + v10 * fy;
    float gr = v01 * (1.f - fy) + v11 * fy;
    out[tid] = gl * (1.f - fx) + gr * fx;
}

extern "C" void kernel_launch(void* const* d_in, const int* in_sizes, int n_in,
                              void* d_out, int out_size, void* d_ws, size_t ws_size,
                              hipStream_t stream) {
    const float* enc   = (const float*)d_in[0];
    const float* ipose = (const float*)d_in[1];
    const float* tpose = (const float*)d_in[2];
    const float* focal = (const float*)d_in[3];
    const float* znear = (const float*)d_in[4];
    const float* zfar  = (const float*)d_in[5];
    const float* W1 = (const float*)d_in[7];
    const float* B1 = (const float*)d_in[8];
    const float* W2 = (const float*)d_in[9];
    const float* B2 = (const float*)d_in[10];
    const float* W3 = (const float*)d_in[11];
    const float* B3 = (const float*)d_in[12];

    float* out = (float*)d_out;
    const int nrays = NRAYS;                             // 18432
    const int nout  = NS * NVT * NC * NH * NW;           // 1179648
    const size_t enc_t_bytes = (size_t)NS * NVIN * NC * DHW * 4;   // 226.5 MB
    const size_t rhalf_bytes = (size_t)nrays * NC * 4;             // 1.18 MB
    const size_t wfrag_bytes = 16 * 64 * 8 * sizeof(short);        // 16 KB
    const size_t xbuf_bytes  = (size_t)NSAMP * NC * 4;             // 75.5 MB

    if (ws_size >= enc_t_bytes + rhalf_bytes + 2 * wfrag_bytes + xbuf_bytes) {
        char* base = (char*)d_ws;
        float* enc_t = (float*)base;                      base += enc_t_bytes;
        float* rhalf = (float*)base;                      base += rhalf_bytes;
        short* whi   = (short*)base;                      base += wfrag_bytes;
        short* wlo   = (short*)base;                      base += wfrag_bytes;
        float* xbuf  = (float*)base;

        wprep_kernel<<<4, 256, 0, stream>>>(W1, W2, W3, whi, wlo);
        transpose_kernel<<<NS * NVIN * NTILE, 256, 0, stream>>>(enc, enc_t);
        gather_kernel<<<nrays, 256, 0, stream>>>(
            enc_t, ipose, tpose, focal, znear, zfar, xbuf);
        mlp_kernel<<<nrays / 4, 256, 0, stream>>>(
            xbuf, znear, zfar, whi, wlo, B1, B2, B3, rhalf);
        upsample_kernel<<<nout / 256, 256, 0, stream>>>(rhalf, out);
    } else {
        float* rhalf = (float*)d_ws;
        render_kernel<<<nrays / 4, 256, 0, stream>>>(
            enc, ipose, tpose, focal, znear, zfar,
            W1, B1, W2, B2, W3, B3, rhalf);
        upsample_kernel<<<nout / 256, 256, 0, stream>>>(rhalf, out);
    }
}

// Round 6
// 598.253 us; speedup vs baseline: 1.0309x; 1.0152x over previous
//
#include <hip/hip_runtime.h>
#include <hip/hip_bf16.h>
#include <math.h>

// Problem constants (fixed by setup_inputs)
#define NS   2
#define NVIN 3
#define NVT  4
#define NC   16
#define ND   64
#define NH   96
#define NW   96
#define HWH  48          // half res h=w
#define SPR  64
#define DHW  (ND*NH*NW)  // 589824
#define NTILE (DHW / 64) // 9216 — NOT a power of two
#define NSAMP (NS*NVT*HWH*HWH*SPR)   // 1179648 samples
#define NRAYS (NS*NVT*HWH*HWH)       // 18432 (% 8 == 0)

typedef __attribute__((ext_vector_type(8))) short bfrag;   // 8 bf16 (4 VGPR)
typedef __attribute__((ext_vector_type(4))) float cfrag;   // 4 fp32 acc
typedef __attribute__((ext_vector_type(4))) float f32x4;
typedef __attribute__((ext_vector_type(4))) int   i32x4;

#define MFMA16 __builtin_amdgcn_mfma_f32_16x16x32_bf16

// Wave-local LDS ordering: each wave's LDS slice is private, so a block
// barrier is never needed — only completion/ordering of THIS wave's DS ops.
// (R1 lesson: do NOT fuse the latency-bound gather into the MLP kernel.)
#define WAVE_LDS_SYNC() asm volatile("s_waitcnt lgkmcnt(0)" ::: "memory")

__device__ __forceinline__ short f2bf(float x) {
    union { __hip_bfloat16 b; short s; } cv;
    cv.b = __float2bfloat16(x);
    return cv.s;
}
__device__ __forceinline__ float bf2f(short s) {
    union { unsigned int u; float f; } cv;
    cv.u = ((unsigned int)(unsigned short)s) << 16;
    return cv.f;
}

// Build hi/lo bf16 A-fragment from 8 consecutive fp32 (LDS or global).
// Verified layout (m120): A[m=lane&15][k=(lane>>4)*8+j], j=0..7.
__device__ __forceinline__ void mk_frag(const float* p, bfrag& ah, bfrag& al) {
    float4 v0 = *(const float4*)p;
    float4 v1 = *(const float4*)(p + 4);
    float e[8] = {v0.x, v0.y, v0.z, v0.w, v1.x, v1.y, v1.z, v1.w};
    #pragma unroll
    for (int j = 0; j < 8; j++) {
        short h = f2bf(e[j]);
        ah[j] = h;
        al[j] = f2bf(e[j] - bf2f(h));
    }
}

// ---------------------------------------------------------------------------
// Weight-fragment prep (R7-verified): split W1/W2/W3 into bf16 hi/lo,
// fragment-linear so each lane loads its B-fragment with one dwordx4.
// ---------------------------------------------------------------------------
__global__ __launch_bounds__(256) void wprep_kernel(
    const float* __restrict__ W1, const float* __restrict__ W2,
    const float* __restrict__ W3, short* __restrict__ whi, short* __restrict__ wlo)
{
    int t = blockIdx.x * 256 + threadIdx.x;   // 1024 total
    int f = t >> 6, L = t & 63;
    int q = L >> 4, li = L & 15;
    #pragma unroll
    for (int j = 0; j < 8; j++) {
        int kloc = q * 8 + j;                 // 0..31
        float w = 0.f;
        if (f < 4) {
            int n = f * 16 + li, k = kloc;
            if (k < 16) w = W1[k * 64 + n];
        } else if (f < 12) {
            int kt = (f - 4) >> 2, nt = (f - 4) & 3;
            w = W2[(kt * 32 + kloc) * 64 + nt * 16 + li];
        } else {
            int kt = (f - 12) >> 1, nt = (f - 12) & 1;
            int n = nt * 16 + li;
            if (n < 17) w = W3[(kt * 32 + kloc) * 17 + n];
        }
        short h = f2bf(w);
        whi[(f * 64 + L) * 8 + j] = h;
        wlo[(f * 64 + L) * 8 + j] = f2bf(w - bf2f(h));
    }
}

// ---------------------------------------------------------------------------
// LDS-tiled transpose enc [6][16][DHW] -> enc_t [6][DHW][16].
// ---------------------------------------------------------------------------
__global__ __launch_bounds__(256) void transpose_kernel(
    const float* __restrict__ in, float* __restrict__ out)
{
    __shared__ float tile[NC][64 + 4];
    const int t   = threadIdx.x;
    const int blk = blockIdx.x;
    const int vox0 = (blk % NTILE) * 64;
    const int sv   = blk / NTILE;

    const int c  = t >> 4;
    const int vg = (t & 15) * 4;
    const float* src = in + ((size_t)sv * NC + c) * DHW + vox0 + vg;
    float4 v = *(const float4*)src;
    tile[c][vg + 0] = v.x; tile[c][vg + 1] = v.y;
    tile[c][vg + 2] = v.z; tile[c][vg + 3] = v.w;
    __syncthreads();

    const int ov = t >> 2;
    const int oc = (t & 3) * 4;
    float4 w = make_float4(tile[oc + 0][ov], tile[oc + 1][ov],
                           tile[oc + 2][ov], tile[oc + 3][ov]);
    float* dst = out + ((size_t)sv * DHW + vox0 + ov) * NC + oc;
    *(float4*)dst = w;
}

// ---------------------------------------------------------------------------
// Gather v6 (two-phase within-wave; R5 post-mortem: VALUBusy 92% => VALU-
// issue-bound via 8x-redundant geometry, AND load batching failed at codegen
// (VGPR=36 => serialized load->fma)).
//  Phase 1: lane = depth sample. Geometry computed ONCE per (sample,view);
//   8 full corner weights + 8 final byte offsets written to per-wave LDS
//   (stride 52 words: 16B-aligned rows, ~2-way-conflict reads).
//  Phase 2: 4 passes of quad-per-sample (c4 channel quads). Weights/offsets
//   read from LDS (4-lane broadcast); the 8 corner loads per view issued as
//   inline-asm global_load_dwordx4 (SGPR base + 32b voffset) then a single
//   s_waitcnt vmcnt(0) + sched_barrier(0) fence (rule-18) before the FMAs —
//   guarantees 8 loads in flight per wave regardless of regalloc.
//  No block barriers anywhere: all LDS traffic is wave-private (R2 pattern).
//  Math identical to R3/R5: same weight association ((wx*wy)*wz), same
//  per-axis validity zeroing, same corner order, same view-major summation.
// ---------------------------------------------------------------------------
__global__ __launch_bounds__(256) void gather_kernel(
    const float* __restrict__ enc_t,
    const float* __restrict__ ipose,
    const float* __restrict__ tpose,
    const float* __restrict__ focal_p,
    const float* __restrict__ znear_p,
    const float* __restrict__ zfar_p,
    float* __restrict__ xbuf)
{
    // block = 4 waves = 4 rays; XCD-chunked swizzle on block index (R3 win)
    const int blk  = (blockIdx.x & 7) * ((NRAYS / 4) >> 3) + (blockIdx.x >> 3);
    const int lane = threadIdx.x & 63;
    const int wv   = threadIdx.x >> 6;
    const int ray  = blk * 4 + wv;
    const int px   = ray % HWH;
    const int py   = (ray / HWH) % HWH;
    const int b    = ray / (HWH * HWH);
    const int s    = b >> 2;

    const float focal = focal_p[0];
    const float znear = znear_p[0];
    const float zfar  = zfar_p[0];

    // per-wave LDS slice: 64 samples x 52 words (3 views x {8 wgt, 8 off})
    __shared__ float lds[4 * 64 * 52];     // 53.2 KB -> 3 blocks/CU

    const float* P = tpose + b * 16;
    float ysc = ((py + 0.5f) / (float)HWH) * 2.f - 1.f;
    float xsc = ((px + 0.5f) / (float)HWH) * 2.f - 1.f;
    float dcx = xsc / focal, dcy = -ysc / focal, dcz = -1.f;
    float dirx = P[0]*dcx + P[1]*dcy + P[2]*dcz;
    float diry = P[4]*dcx + P[5]*dcy + P[6]*dcz;
    float dirz = P[8]*dcx + P[9]*dcy + P[10]*dcz;

    // Per-view hoist (R0/R5-verified algebra): local = R^T(o-t) + tv*R^T dir
    float lox[NVIN], loy[NVIN], loz[NVIN];
    float ldx[NVIN], ldy[NVIN], ldz[NVIN];
    #pragma unroll
    for (int v = 0; v < NVIN; v++) {
        const float* E = ipose + (s * NVIN + v) * 16;
        float qx = P[3] - E[3], qy = P[7] - E[7], qz = P[11] - E[11];
        lox[v] = E[0]*qx + E[4]*qy + E[8]*qz;
        loy[v] = E[1]*qx + E[5]*qy + E[9]*qz;
        loz[v] = E[2]*qx + E[6]*qy + E[10]*qz;
        ldx[v] = E[0]*dirx + E[4]*diry + E[8]*dirz;
        ldy[v] = E[1]*dirx + E[5]*diry + E[9]*dirz;
        ldz[v] = E[2]*dirx + E[6]*diry + E[10]*dirz;
    }

    const float minz = focal * znear, maxz = focal * zfar;
    const float inv3 = 1.f / 3.f;

    // ---- phase 1: per-lane sample geometry -> LDS ----
    {
        const int d = lane;
        float tv = znear + (zfar - znear) * ((float)d / (float)(SPR - 1));
        float* row = lds + (wv * 64 + d) * 52;
        #pragma unroll
        for (int v = 0; v < NVIN; v++) {
            float lx = lox[v] + tv * ldx[v];
            float ly = loy[v] + tv * ldy[v];
            float lz = loz[v] + tv * ldz[v];
            float zz = -lz;
            float u  = lx / zz * focal;
            float vv = ly / zz * focal;
            float wd = 2.f * (zz - minz) / (maxz - minz) - 1.f;
            float ix = ((u   + 1.f) * NW - 1.f) * 0.5f;
            float iy = ((-vv + 1.f) * NH - 1.f) * 0.5f;
            float iz = ((-wd + 1.f) * ND - 1.f) * 0.5f;
            float x0 = floorf(ix), y0 = floorf(iy), z0 = floorf(iz);
            float x1 = x0 + 1.f,   y1 = y0 + 1.f,   z1 = z0 + 1.f;

            float wxa0 = 1.f - fabsf(ix - x0), wxa1 = 1.f - fabsf(ix - x1);
            float wya0 = 1.f - fabsf(iy - y0), wya1 = 1.f - fabsf(iy - y1);
            float wza0 = 1.f - fabsf(iz - z0), wza1 = 1.f - fabsf(iz - z1);
            wxa0 = (x0 >= 0.f && x0 < (float)NW) ? wxa0 : 0.f;
            wxa1 = (x1 >= 0.f && x1 < (float)NW) ? wxa1 : 0.f;
            wya0 = (y0 >= 0.f && y0 < (float)NH) ? wya0 : 0.f;
            wya1 = (y1 >= 0.f && y1 < (float)NH) ? wya1 : 0.f;
            wza0 = (z0 >= 0.f && z0 < (float)ND) ? wza0 : 0.f;
            wza1 = (z1 >= 0.f && z1 < (float)ND) ? wza1 : 0.f;

            int xi0 = min(max((int)x0, 0), NW - 1), xi1 = min(max((int)x1, 0), NW - 1);
            int yi0 = min(max((int)y0, 0), NH - 1), yi1 = min(max((int)y1, 0), NH - 1);
            int zi0 = min(max((int)z0, 0), ND - 1), zi1 = min(max((int)z1, 0), ND - 1);
            int o00 = (zi0 * NH + yi0) * NW, o01 = (zi0 * NH + yi1) * NW;
            int o10 = (zi1 * NH + yi0) * NW, o11 = (zi1 * NH + yi1) * NW;

            const int sb = (s * NVIN + v) * (DHW * NC * 4);   // view slab, bytes

            // corner order k = dz*4 + dy*2 + dx (same as R3/R5)
            f32x4 w0 = { (wxa0*wya0)*wza0, (wxa1*wya0)*wza0,
                         (wxa0*wya1)*wza0, (wxa1*wya1)*wza0 };
            f32x4 w1 = { (wxa0*wya0)*wza1, (wxa1*wya0)*wza1,
                         (wxa0*wya1)*wza1, (wxa1*wya1)*wza1 };
            i32x4 o0 = { sb + (o00 + xi0) * 64, sb + (o00 + xi1) * 64,
                         sb + (o01 + xi0) * 64, sb + (o01 + xi1) * 64 };
            i32x4 o1 = { sb + (o10 + xi0) * 64, sb + (o10 + xi1) * 64,
                         sb + (o11 + xi0) * 64, sb + (o11 + xi1) * 64 };

            *(f32x4*)(row + v*16 + 0)  = w0;
            *(f32x4*)(row + v*16 + 4)  = w1;
            *(i32x4*)(row + v*16 + 8)  = o0;
            *(i32x4*)(row + v*16 + 12) = o1;
        }
    }
    WAVE_LDS_SYNC();   // this wave's geometry visible to its own lanes

    // ---- phase 2: quad-cooperative loads, 8-deep via inline asm ----
    const int c4 = lane & 3;
    const int cb = c4 * 16;                  // channel-quad byte offset

    #pragma unroll 1
    for (int pass = 0; pass < 4; pass++) {
        const int sm = pass * 16 + (lane >> 2);
        const float* row = lds + (wv * 64 + sm) * 52;
        f32x4 acc = {0.f, 0.f, 0.f, 0.f};

        #pragma unroll
        for (int v = 0; v < NVIN; v++) {
            f32x4 wq0 = *(const f32x4*)(row + v*16 + 0);
            f32x4 wq1 = *(const f32x4*)(row + v*16 + 4);
            i32x4 oq0 = *(const i32x4*)(row + v*16 + 8);
            i32x4 oq1 = *(const i32x4*)(row + v*16 + 12);

            f32x4 a0, a1, a2, a3, a4, a5, a6, a7;
            int v0 = oq0.x + cb, v1 = oq0.y + cb, v2 = oq0.z + cb, v3 = oq0.w + cb;
            int v4 = oq1.x + cb, v5 = oq1.y + cb, v6 = oq1.z + cb, v7 = oq1.w + cb;
            asm volatile("global_load_dwordx4 %0, %1, %2" : "=&v"(a0) : "v"(v0), "s"(enc_t));
            asm volatile("global_load_dwordx4 %0, %1, %2" : "=&v"(a1) : "v"(v1), "s"(enc_t));
            asm volatile("global_load_dwordx4 %0, %1, %2" : "=&v"(a2) : "v"(v2), "s"(enc_t));
            asm volatile("global_load_dwordx4 %0, %1, %2" : "=&v"(a3) : "v"(v3), "s"(enc_t));
            asm volatile("global_load_dwordx4 %0, %1, %2" : "=&v"(a4) : "v"(v4), "s"(enc_t));
            asm volatile("global_load_dwordx4 %0, %1, %2" : "=&v"(a5) : "v"(v5), "s"(enc_t));
            asm volatile("global_load_dwordx4 %0, %1, %2" : "=&v"(a6) : "v"(v6), "s"(enc_t));
            asm volatile("global_load_dwordx4 %0, %1, %2" : "=&v"(a7) : "v"(v7), "s"(enc_t));
            asm volatile("s_waitcnt vmcnt(0)" ::: "memory");
            __builtin_amdgcn_sched_barrier(0);   // rule-18: pin FMAs after wait

            acc += wq0.x * a0;  acc += wq0.y * a1;
            acc += wq0.z * a2;  acc += wq0.w * a3;
            acc += wq1.x * a4;  acc += wq1.y * a5;
            acc += wq1.z * a6;  acc += wq1.w * a7;
        }
        ((f32x4*)xbuf)[(ray * 64 + sm) * 4 + c4] = acc * inv3;
    }
}

// ---------------------------------------------------------------------------
// MFMA MLP + composite (R7-verified pipeline, A-frags from global xbuf).
// One wave per ray; block = 4 rays. bf16 hi/lo 3-product = fp32-accurate.
// R2: sbuf slices are per-wave, so every __syncthreads() is replaced by a
// wave-local lgkmcnt(0) — zero cross-wave barriers (verified win).
// ---------------------------------------------------------------------------
__global__ __launch_bounds__(256) void mlp_kernel(
    const float* __restrict__ xbuf,
    const float* __restrict__ znear_p,
    const float* __restrict__ zfar_p,
    const short* __restrict__ whi, const short* __restrict__ wlo,
    const float* __restrict__ B1, const float* __restrict__ B2,
    const float* __restrict__ B3,
    float* __restrict__ rhalf)
{
    const int lane = threadIdx.x & 63;
    const int ray  = blockIdx.x * 4 + (threadIdx.x >> 6);
    const int px   = ray % HWH;
    const int py   = (ray / HWH) % HWH;
    const int b    = ray / (HWH * HWH);

    const float znear = znear_p[0];
    const float zfar  = zfar_p[0];

    __shared__ float sbuf[4][64][36];   // per-wave 64x36 staging (36.9 KB)
    float (*B)[36] = sbuf[threadIdx.x >> 6];
    const int li = lane & 15, q = lane >> 4;
    const float* X = xbuf + (size_t)ray * 64 * NC;   // this ray's 64x16 rows

    float b1v[4], b2v[4], b3v[2];
    #pragma unroll
    for (int nt = 0; nt < 4; nt++) { b1v[nt] = B1[nt*16 + li]; b2v[nt] = B2[nt*16 + li]; }
    b3v[0] = B3[li];
    b3v[1] = (li == 0) ? B3[16] : 0.f;

    // layer-1 A-frags straight from global X (K=16; q>=2 lanes are zero pad)
    bfrag xah[4], xal[4];
    bfrag zb = {0,0,0,0,0,0,0,0};
    #pragma unroll
    for (int mt = 0; mt < 4; mt++) {
        if (q < 2) mk_frag(X + (mt*16 + li) * NC + q * 8, xah[mt], xal[mt]);
        else { xah[mt] = zb; xal[mt] = zb; }
    }

    cfrag zc = {0.f, 0.f, 0.f, 0.f};
    cfrag h2acc[4][4];
    #pragma unroll
    for (int mt = 0; mt < 4; mt++)
        #pragma unroll
        for (int nt = 0; nt < 4; nt++) h2acc[mt][nt] = zc;

    #pragma unroll
    for (int c1 = 0; c1 < 2; c1++) {
        cfrag h1[4][2];
        #pragma unroll
        for (int nt2 = 0; nt2 < 2; nt2++) {
            int f = 2*c1 + nt2;
            bfrag bh = *(const bfrag*)(whi + (f*64 + lane)*8);
            bfrag bl = *(const bfrag*)(wlo + (f*64 + lane)*8);
            #pragma unroll
            for (int mt = 0; mt < 4; mt++) {
                cfrag a = zc;
                a = MFMA16(xal[mt], bh, a, 0, 0, 0);
                a = MFMA16(xah[mt], bl, a, 0, 0, 0);
                a = MFMA16(xah[mt], bh, a, 0, 0, 0);
                h1[mt][nt2] = a;
            }
        }
        WAVE_LDS_SYNC();   // prior iter's staging reads ordered before writes
        #pragma unroll
        for (int mt = 0; mt < 4; mt++)
            #pragma unroll
            for (int nt2 = 0; nt2 < 2; nt2++)
                #pragma unroll
                for (int r = 0; r < 4; r++)
                    B[mt*16 + q*4 + r][nt2*16 + li] =
                        fmaxf(h1[mt][nt2][r] + b1v[2*c1 + nt2], 0.f);
        WAVE_LDS_SYNC();   // this wave's writes visible to its own reads
        bfrag hah[4], hal[4];
        #pragma unroll
        for (int mt = 0; mt < 4; mt++)
            mk_frag(&B[mt*16 + li][q*8], hah[mt], hal[mt]);
        #pragma unroll
        for (int nt = 0; nt < 4; nt++) {
            int f = 4 + c1*4 + nt;
            bfrag bh = *(const bfrag*)(whi + (f*64 + lane)*8);
            bfrag bl = *(const bfrag*)(wlo + (f*64 + lane)*8);
            #pragma unroll
            for (int mt = 0; mt < 4; mt++) {
                cfrag a = h2acc[mt][nt];
                a = MFMA16(hal[mt], bh, a, 0, 0, 0);
                a = MFMA16(hah[mt], bl, a, 0, 0, 0);
                a = MFMA16(hah[mt], bh, a, 0, 0, 0);
                h2acc[mt][nt] = a;
            }
        }
    }

    cfrag oacc[4][2];
    #pragma unroll
    for (int mt = 0; mt < 4; mt++)
        #pragma unroll
        for (int nt = 0; nt < 2; nt++) oacc[mt][nt] = zc;

    #pragma unroll
    for (int c2 = 0; c2 < 2; c2++) {
        WAVE_LDS_SYNC();
        #pragma unroll
        for (int mt = 0; mt < 4; mt++)
            #pragma unroll
            for (int nt2 = 0; nt2 < 2; nt2++)
                #pragma unroll
                for (int r = 0; r < 4; r++)
                    B[mt*16 + q*4 + r][nt2*16 + li] =
                        fmaxf(h2acc[mt][2*c2 + nt2][r] + b2v[2*c2 + nt2], 0.f);
        WAVE_LDS_SYNC();
        bfrag hah[4], hal[4];
        #pragma unroll
        for (int mt = 0; mt < 4; mt++)
            mk_frag(&B[mt*16 + li][q*8], hah[mt], hal[mt]);
        #pragma unroll
        for (int nt = 0; nt < 2; nt++) {
            int f = 12 + c2*2 + nt;
            bfrag bh = *(const bfrag*)(whi + (f*64 + lane)*8);
            bfrag bl = *(const bfrag*)(wlo + (f*64 + lane)*8);
            #pragma unroll
            for (int mt = 0; mt < 4; mt++) {
                cfrag a = oacc[mt][nt];
                a = MFMA16(hal[mt], bh, a, 0, 0, 0);
                a = MFMA16(hah[mt], bl, a, 0, 0, 0);
                a = MFMA16(hah[mt], bh, a, 0, 0, 0);
                oacc[mt][nt] = a;
            }
        }
    }

    // O (C-layout) -> LDS -> per-lane (lane = its own sample row)
    WAVE_LDS_SYNC();
    #pragma unroll
    for (int mt = 0; mt < 4; mt++)
        #pragma unroll
        for (int nt = 0; nt < 2; nt++) {
            int ch = nt*16 + li;
            if (ch < 17) {
                #pragma unroll
                for (int r = 0; r < 4; r++)
                    B[mt*16 + q*4 + r][ch] = oacc[mt][nt][r] + b3v[nt];
            }
        }
    WAVE_LDS_SYNC();
    float4 o0 = *(float4*)&B[lane][0];
    float4 o1 = *(float4*)&B[lane][4];
    float4 o2 = *(float4*)&B[lane][8];
    float4 o3 = *(float4*)&B[lane][12];
    float o16 = B[lane][16];

    float density = fmaxf(o0.x, 0.f);
    float orgb[16] = {o0.y, o0.z, o0.w, o1.x, o1.y, o1.z, o1.w, o2.x,
                      o2.y, o2.z, o2.w, o3.x, o3.y, o3.z, o3.w, o16};

    // feats re-read from L2-hot xbuf (saves 16 live VGPRs across the MLP)
    float4 fx0 = *(const float4*)(X + lane * NC + 0);
    float4 fx1 = *(const float4*)(X + lane * NC + 4);
    float4 fx2 = *(const float4*)(X + lane * NC + 8);
    float4 fx3 = *(const float4*)(X + lane * NC + 12);
    float feats[16] = {fx0.x, fx0.y, fx0.z, fx0.w, fx1.x, fx1.y, fx1.z, fx1.w,
                       fx2.x, fx2.y, fx2.z, fx2.w, fx3.x, fx3.y, fx3.z, fx3.w};

    // ---- per-ray compositing ----
    float tv = znear + (zfar - znear) * ((float)lane / (float)(SPR - 1));
    float tn = znear + (zfar - znear) * ((float)(lane + 1) / (float)(SPR - 1));
    float delta = (lane < SPR - 1) ? (tn - tv) : 1e10f;
    float sigdel = density * delta;
    float alpha = 1.f - expf(-sigdel);
    float csum = sigdel;
    #pragma unroll
    for (int off = 1; off < 64; off <<= 1) {
        float nb = __shfl_up(csum, off, 64);
        if (lane >= off) csum += nb;
    }
    float wray = alpha * expf(-csum);

    #pragma unroll
    for (int c = 0; c < NC; c++) {
        float val = wray * (feats[c] + orgb[c]);
        #pragma unroll
        for (int off = 32; off >= 1; off >>= 1)
            val += __shfl_down(val, off, 64);
        if (lane == 0)
            rhalf[((b * NC + c) * HWH + py) * HWH + px] = val;
    }
}

// ---------------------------------------------------------------------------
// Scalar fallback (R6-proven) — only if ws too small.
// ---------------------------------------------------------------------------
__device__ __forceinline__ void mlp_and_composite(
    const float feats[NC], int lane, int b, int py, int px,
    float tv, float znear, float zfar,
    const float* __restrict__ W1, const float* __restrict__ B1,
    const float* __restrict__ W2, const float* __restrict__ B2,
    const float* __restrict__ W3, const float* __restrict__ B3,
    float* __restrict__ rhalf)
{
    float outa[17];
    #pragma unroll
    for (int c = 0; c < 17; c++) outa[c] = B3[c];
    for (int kc = 0; kc < 4; kc++) {
        float h2c[16];
        #pragma unroll
        for (int k = 0; k < 16; k++) h2c[k] = B2[kc * 16 + k];
        #pragma unroll 4
        for (int j = 0; j < 64; j++) {
            float a = B1[j];
            #pragma unroll
            for (int i = 0; i < NC; i++) a += feats[i] * W1[i * 64 + j];
            a = fmaxf(a, 0.f);
            const float* w2p = W2 + j * 64 + kc * 16;
            #pragma unroll
            for (int k = 0; k < 16; k++) h2c[k] += a * w2p[k];
        }
        #pragma unroll
        for (int k = 0; k < 16; k++) {
            float hv = fmaxf(h2c[k], 0.f);
            const float* w3p = W3 + (kc * 16 + k) * 17;
            #pragma unroll
            for (int c = 0; c < 17; c++) outa[c] += hv * w3p[c];
        }
    }
    float density = fmaxf(outa[0], 0.f);
    float tn = znear + (zfar - znear) * ((float)(lane + 1) / (float)(SPR - 1));
    float delta = (lane < SPR - 1) ? (tn - tv) : 1e10f;
    float sigdel = density * delta;
    float alpha = 1.f - expf(-sigdel);
    float csum = sigdel;
    #pragma unroll
    for (int off = 1; off < 64; off <<= 1) {
        float nb = __shfl_up(csum, off, 64);
        if (lane >= off) csum += nb;
    }
    float wray = alpha * expf(-csum);
    #pragma unroll
    for (int c = 0; c < NC; c++) {
        float val = wray * (feats[c] + outa[1 + c]);
        #pragma unroll
        for (int off = 32; off >= 1; off >>= 1)
            val += __shfl_down(val, off, 64);
        if (lane == 0)
            rhalf[((b * NC + c) * HWH + py) * HWH + px] = val;
    }
}

__global__ __launch_bounds__(256) void render_kernel(
    const float* __restrict__ enc,
    const float* __restrict__ ipose,
    const float* __restrict__ tpose,
    const float* __restrict__ focal_p,
    const float* __restrict__ znear_p,
    const float* __restrict__ zfar_p,
    const float* __restrict__ W1, const float* __restrict__ B1,
    const float* __restrict__ W2, const float* __restrict__ B2,
    const float* __restrict__ W3, const float* __restrict__ B3,
    float* __restrict__ rhalf)
{
    const int lane = threadIdx.x & 63;
    const int ray  = blockIdx.x * 4 + (threadIdx.x >> 6);
    const int px   = ray % HWH;
    const int py   = (ray / HWH) % HWH;
    const int b    = ray / (HWH * HWH);
    const int s    = b >> 2;
    const float focal = focal_p[0];
    const float znear = znear_p[0];
    const float zfar  = zfar_p[0];
    const float* P = tpose + b * 16;
    float ysc = ((py + 0.5f) / (float)HWH) * 2.f - 1.f;
    float xsc = ((px + 0.5f) / (float)HWH) * 2.f - 1.f;
    float dcx = xsc / focal, dcy = -ysc / focal, dcz = -1.f;
    float dirx = P[0]*dcx + P[1]*dcy + P[2]*dcz;
    float diry = P[4]*dcx + P[5]*dcy + P[6]*dcz;
    float dirz = P[8]*dcx + P[9]*dcy + P[10]*dcz;
    float tv  = znear + (zfar - znear) * ((float)lane / (float)(SPR - 1));
    float ptx = P[3] + tv * dirx, pty = P[7] + tv * diry, ptz = P[11] + tv * dirz;
    float feats[NC];
    #pragma unroll
    for (int c = 0; c < NC; c++) feats[c] = 0.f;
    const float minz = focal * znear, maxz = focal * zfar;
    for (int v = 0; v < NVIN; v++) {
        const float* E = ipose + (s * NVIN + v) * 16;
        float qx = ptx - E[3], qy = pty - E[7], qz = ptz - E[11];
        float lx = E[0]*qx + E[4]*qy + E[8]*qz;
        float ly = E[1]*qx + E[5]*qy + E[9]*qz;
        float lz = E[2]*qx + E[6]*qy + E[10]*qz;
        float zz = -lz;
        float u  = lx / zz * focal;
        float vv = ly / zz * focal;
        float wd = 2.f * (zz - minz) / (maxz - minz) - 1.f;
        float ix = ((u   + 1.f) * NW - 1.f) * 0.5f;
        float iy = ((-vv + 1.f) * NH - 1.f) * 0.5f;
        float iz = ((-wd + 1.f) * ND - 1.f) * 0.5f;
        float x0 = floorf(ix), y0 = floorf(iy), z0 = floorf(iz);
        float wgt[8]; int idx[8];
        #pragma unroll
        for (int k = 0; k < 8; k++) {
            float xc = x0 + (k & 1), yc = y0 + ((k >> 1) & 1), zc = z0 + (k >> 2);
            float wt = (1.f - fabsf(ix - xc)) * (1.f - fabsf(iy - yc)) * (1.f - fabsf(iz - zc));
            bool valid = (xc >= 0.f) && (xc < (float)NW) &&
                         (yc >= 0.f) && (yc < (float)NH) &&
                         (zc >= 0.f) && (zc < (float)ND);
            wgt[k] = valid ? wt : 0.f;
            int xi = min(max((int)xc, 0), NW - 1);
            int yi = min(max((int)yc, 0), NH - 1);
            int zi = min(max((int)zc, 0), ND - 1);
            idx[k] = (zi * NH + yi) * NW + xi;
        }
        const float* VB = enc + (size_t)(s * NVIN + v) * NC * DHW;
        #pragma unroll
        for (int c = 0; c < NC; c++) {
            const float* vc = VB + c * DHW;
            float acc = 0.f;
            #pragma unroll
            for (int k = 0; k < 8; k++) acc += wgt[k] * vc[idx[k]];
            feats[c] += acc;
        }
    }
    #pragma unroll
    for (int c = 0; c < NC; c++) feats[c] *= (1.f / 3.f);
    mlp_and_composite(feats, lane, b, py, px, tv, znear, zfar,
                      W1, B1, W2, B2, W3, B3, rhalf);
}

// 2x bilinear upsample, align_corners=True.
__global__ __launch_bounds__(256) void upsample_kernel(
    const float* __restrict__ in, float* __restrict__ out)
{
    int tid = blockIdx.x * 256 + threadIdx.x;
    int ox = tid % NW;
    int oy = (tid / NW) % NH;
    int c  = (tid / (NW * NH)) % NC;
    int b  = tid / (NW * NH * NC);
    const float sc = (float)((HWH - 1) / (double)(NH - 1)); // 47/95
    float pyf = oy * sc;
    float pxf = ox * sc;
    int y0 = (int)floorf(pyf); int y1 = min(y0 + 1, HWH - 1); float fy = pyf - y0;
    int x0 = (int)floorf(pxf); int x1 = min(x0 + 1, HWH - 1); float fx = pxf - x0;
    const float* src = in + (b * NC + c) * HWH * HWH;
    float v00 = src[y0 * HWH + x0], v01 = src[y0 * HWH + x1];
    float v10 = src[y1 * HWH + x0], v11 = src[y1 * HWH + x1];
    float gl = v00 * (1.f - fy) + v10 * fy;
    float gr = v01 * (1.f - fy) + v11 * fy;
    out[tid] = gl * (1.f - fx) + gr * fx;
}

extern "C" void kernel_launch(void* const* d_in, const int* in_sizes, int n_in,
                              void* d_out, int out_size, void* d_ws, size_t ws_size,
                              hipStream_t stream) {
    const float* enc   = (const float*)d_in[0];
    const float* ipose = (const float*)d_in[1];
    const float* tpose = (const float*)d_in[2];
    const float* focal = (const float*)d_in[3];
    const float* znear = (const float*)d_in[4];
    const float* zfar  = (const float*)d_in[5];
    const float* W1 = (const float*)d_in[7];
    const float* B1 = (const float*)d_in[8];
    const float* W2 = (const float*)d_in[9];
    const float* B2 = (const float*)d_in[10];
    const float* W3 = (const float*)d_in[11];
    const float* B3 = (const float*)d_in[12];

    float* out = (float*)d_out;
    const int nrays = NRAYS;                             // 18432
    const int nout  = NS * NVT * NC * NH * NW;           // 1179648
    const size_t enc_t_bytes = (size_t)NS * NVIN * NC * DHW * 4;   // 226.5 MB
    const size_t rhalf_bytes = (size_t)nrays * NC * 4;             // 1.18 MB
    const size_t wfrag_bytes = 16 * 64 * 8 * sizeof(short);        // 16 KB
    const size_t xbuf_bytes  = (size_t)NSAMP * NC * 4;             // 75.5 MB

    if (ws_size >= enc_t_bytes + rhalf_bytes + 2 * wfrag_bytes + xbuf_bytes) {
        char* base = (char*)d_ws;
        float* enc_t = (float*)base;                      base += enc_t_bytes;
        float* rhalf = (float*)base;                      base += rhalf_bytes;
        short* whi   = (short*)base;                      base += wfrag_bytes;
        short* wlo   = (short*)base;                      base += wfrag_bytes;
        float* xbuf  = (float*)base;

        wprep_kernel<<<4, 256, 0, stream>>>(W1, W2, W3, whi, wlo);
        transpose_kernel<<<NS * NVIN * NTILE, 256, 0, stream>>>(enc, enc_t);
        gather_kernel<<<nrays / 4, 256, 0, stream>>>(
            enc_t, ipose, tpose, focal, znear, zfar, xbuf);
        mlp_kernel<<<nrays / 4, 256, 0, stream>>>(
            xbuf, znear, zfar, whi, wlo, B1, B2, B3, rhalf);
        upsample_kernel<<<nout / 256, 256, 0, stream>>>(rhalf, out);
    } else {
        float* rhalf = (float*)d_ws;
        render_kernel<<<nrays / 4, 256, 0, stream>>>(
            enc, ipose, tpose, focal, znear, zfar,
            W1, B1, W2, B2, W3, B3, rhalf);
        upsample_kernel<<<nout / 256, 256, 0, stream>>>(rhalf, out);
    }
}

// Round 7
// 594.805 us; speedup vs baseline: 1.0369x; 1.0058x over previous
//
#include <hip/hip_runtime.h>
#include <hip/hip_bf16.h>
#include <math.h>

// Problem constants (fixed by setup_inputs)
#define NS   2
#define NVIN 3
#define NVT  4
#define NC   16
#define ND   64
#define NH   96
#define NW   96
#define HWH  48          // half res h=w
#define SPR  64
#define DHW  (ND*NH*NW)  // 589824
#define NTILE (DHW / 64) // 9216 — NOT a power of two
#define NSAMP (NS*NVT*HWH*HWH*SPR)   // 1179648 samples
#define NRAYS (NS*NVT*HWH*HWH)       // 18432 (% 8 == 0)

typedef __attribute__((ext_vector_type(8))) short bfrag;   // 8 bf16 (4 VGPR)
typedef __attribute__((ext_vector_type(4))) float cfrag;   // 4 fp32 acc
typedef __attribute__((ext_vector_type(4))) float f32x4;
typedef __attribute__((ext_vector_type(4))) int   i32x4;

#define MFMA16 __builtin_amdgcn_mfma_f32_16x16x32_bf16

// Wave-local LDS ordering: each wave's LDS slice is private, so a block
// barrier is never needed — only completion/ordering of THIS wave's DS ops.
// (R1 lesson: do NOT fuse the latency-bound gather into the MLP kernel.)
#define WAVE_LDS_SYNC() asm volatile("s_waitcnt lgkmcnt(0)" ::: "memory")

__device__ __forceinline__ short f2bf(float x) {
    union { __hip_bfloat16 b; short s; } cv;
    cv.b = __float2bfloat16(x);
    return cv.s;
}
__device__ __forceinline__ float bf2f(short s) {
    union { unsigned int u; float f; } cv;
    cv.u = ((unsigned int)(unsigned short)s) << 16;
    return cv.f;
}

// Build hi/lo bf16 A-fragment from 8 consecutive fp32 (LDS or global).
// Verified layout (m120): A[m=lane&15][k=(lane>>4)*8+j], j=0..7.
__device__ __forceinline__ void mk_frag(const float* p, bfrag& ah, bfrag& al) {
    float4 v0 = *(const float4*)p;
    float4 v1 = *(const float4*)(p + 4);
    float e[8] = {v0.x, v0.y, v0.z, v0.w, v1.x, v1.y, v1.z, v1.w};
    #pragma unroll
    for (int j = 0; j < 8; j++) {
        short h = f2bf(e[j]);
        ah[j] = h;
        al[j] = f2bf(e[j] - bf2f(h));
    }
}

// ---------------------------------------------------------------------------
// Weight-fragment prep (R7-verified): split W1/W2/W3 into bf16 hi/lo,
// fragment-linear so each lane loads its B-fragment with one dwordx4.
// ---------------------------------------------------------------------------
__global__ __launch_bounds__(256) void wprep_kernel(
    const float* __restrict__ W1, const float* __restrict__ W2,
    const float* __restrict__ W3, short* __restrict__ whi, short* __restrict__ wlo)
{
    int t = blockIdx.x * 256 + threadIdx.x;   // 1024 total
    int f = t >> 6, L = t & 63;
    int q = L >> 4, li = L & 15;
    #pragma unroll
    for (int j = 0; j < 8; j++) {
        int kloc = q * 8 + j;                 // 0..31
        float w = 0.f;
        if (f < 4) {
            int n = f * 16 + li, k = kloc;
            if (k < 16) w = W1[k * 64 + n];
        } else if (f < 12) {
            int kt = (f - 4) >> 2, nt = (f - 4) & 3;
            w = W2[(kt * 32 + kloc) * 64 + nt * 16 + li];
        } else {
            int kt = (f - 12) >> 1, nt = (f - 12) & 1;
            int n = nt * 16 + li;
            if (n < 17) w = W3[(kt * 32 + kloc) * 17 + n];
        }
        short h = f2bf(w);
        whi[(f * 64 + L) * 8 + j] = h;
        wlo[(f * 64 + L) * 8 + j] = f2bf(w - bf2f(h));
    }
}

// ---------------------------------------------------------------------------
// LDS-tiled transpose enc [6][16][DHW] -> enc_t [6][DHW][16].
// ---------------------------------------------------------------------------
__global__ __launch_bounds__(256) void transpose_kernel(
    const float* __restrict__ in, float* __restrict__ out)
{
    __shared__ float tile[NC][64 + 4];
    const int t   = threadIdx.x;
    const int blk = blockIdx.x;
    const int vox0 = (blk % NTILE) * 64;
    const int sv   = blk / NTILE;

    const int c  = t >> 4;
    const int vg = (t & 15) * 4;
    const float* src = in + ((size_t)sv * NC + c) * DHW + vox0 + vg;
    float4 v = *(const float4*)src;
    tile[c][vg + 0] = v.x; tile[c][vg + 1] = v.y;
    tile[c][vg + 2] = v.z; tile[c][vg + 3] = v.w;
    __syncthreads();

    const int ov = t >> 2;
    const int oc = (t & 3) * 4;
    float4 w = make_float4(tile[oc + 0][ov], tile[oc + 1][ov],
                           tile[oc + 2][ov], tile[oc + 3][ov]);
    float* dst = out + ((size_t)sv * DHW + vox0 + ov) * NC + oc;
    *(float4*)dst = w;
}

// ---------------------------------------------------------------------------
// Gather v7. v6 post-mortem: two-phase structure + 8-deep asm loads landed,
// but the 53.2 KB geometry LDS capped occupancy at 3 blocks/CU (12 waves) —
// in-flight lines/CU unchanged (~96). v7 halves the LDS by staging geometry
// for 32 samples at a time (two h-halves; lanes<32 compute phase 1):
// 26.6 KB -> 6 blocks/CU, VGPR-capped ~20 waves/CU, ~160 lines in flight.
// Math identical to v5/v6 (same association, zeroing, corner order).
// ---------------------------------------------------------------------------
__global__ __launch_bounds__(256) void gather_kernel(
    const float* __restrict__ enc_t,
    const float* __restrict__ ipose,
    const float* __restrict__ tpose,
    const float* __restrict__ focal_p,
    const float* __restrict__ znear_p,
    const float* __restrict__ zfar_p,
    float* __restrict__ xbuf)
{
    // block = 4 waves = 4 rays; XCD-chunked swizzle on block index (R3 win)
    const int blk  = (blockIdx.x & 7) * ((NRAYS / 4) >> 3) + (blockIdx.x >> 3);
    const int lane = threadIdx.x & 63;
    const int wv   = threadIdx.x >> 6;
    const int ray  = blk * 4 + wv;
    const int px   = ray % HWH;
    const int py   = (ray / HWH) % HWH;
    const int b    = ray / (HWH * HWH);
    const int s    = b >> 2;

    const float focal = focal_p[0];
    const float znear = znear_p[0];
    const float zfar  = zfar_p[0];

    // per-wave LDS slice: 32 samples x 52 words (3 views x {8 wgt, 8 off})
    __shared__ float lds[4 * 32 * 52];     // 26.6 KB -> 6 blocks/CU
    float* wslice = lds + wv * 32 * 52;

    const float* P = tpose + b * 16;
    float ysc = ((py + 0.5f) / (float)HWH) * 2.f - 1.f;
    float xsc = ((px + 0.5f) / (float)HWH) * 2.f - 1.f;
    float dcx = xsc / focal, dcy = -ysc / focal, dcz = -1.f;
    float dirx = P[0]*dcx + P[1]*dcy + P[2]*dcz;
    float diry = P[4]*dcx + P[5]*dcy + P[6]*dcz;
    float dirz = P[8]*dcx + P[9]*dcy + P[10]*dcz;

    // Per-view hoist (R0/R5-verified algebra): local = R^T(o-t) + tv*R^T dir
    float lox[NVIN], loy[NVIN], loz[NVIN];
    float ldx[NVIN], ldy[NVIN], ldz[NVIN];
    #pragma unroll
    for (int v = 0; v < NVIN; v++) {
        const float* E = ipose + (s * NVIN + v) * 16;
        float qx = P[3] - E[3], qy = P[7] - E[7], qz = P[11] - E[11];
        lox[v] = E[0]*qx + E[4]*qy + E[8]*qz;
        loy[v] = E[1]*qx + E[5]*qy + E[9]*qz;
        loz[v] = E[2]*qx + E[6]*qy + E[10]*qz;
        ldx[v] = E[0]*dirx + E[4]*diry + E[8]*dirz;
        ldy[v] = E[1]*dirx + E[5]*diry + E[9]*dirz;
        ldz[v] = E[2]*dirx + E[6]*diry + E[10]*dirz;
    }

    const float minz = focal * znear, maxz = focal * zfar;
    const float inv3 = 1.f / 3.f;
    const int c4 = lane & 3;
    const int cb = c4 * 16;                  // channel-quad byte offset

    #pragma unroll 1
    for (int h = 0; h < 2; h++) {
        WAVE_LDS_SYNC();   // prior half's LDS reads ordered before overwrite

        // ---- phase 1: lanes<32 compute geometry for samples h*32+lane ----
        if (lane < 32) {
            const int d = h * 32 + lane;
            float tv = znear + (zfar - znear) * ((float)d / (float)(SPR - 1));
            float* row = wslice + lane * 52;
            #pragma unroll
            for (int v = 0; v < NVIN; v++) {
                float lx = lox[v] + tv * ldx[v];
                float ly = loy[v] + tv * ldy[v];
                float lz = loz[v] + tv * ldz[v];
                float zz = -lz;
                float u  = lx / zz * focal;
                float vv = ly / zz * focal;
                float wd = 2.f * (zz - minz) / (maxz - minz) - 1.f;
                float ix = ((u   + 1.f) * NW - 1.f) * 0.5f;
                float iy = ((-vv + 1.f) * NH - 1.f) * 0.5f;
                float iz = ((-wd + 1.f) * ND - 1.f) * 0.5f;
                float x0 = floorf(ix), y0 = floorf(iy), z0 = floorf(iz);
                float x1 = x0 + 1.f,   y1 = y0 + 1.f,   z1 = z0 + 1.f;

                float wxa0 = 1.f - fabsf(ix - x0), wxa1 = 1.f - fabsf(ix - x1);
                float wya0 = 1.f - fabsf(iy - y0), wya1 = 1.f - fabsf(iy - y1);
                float wza0 = 1.f - fabsf(iz - z0), wza1 = 1.f - fabsf(iz - z1);
                wxa0 = (x0 >= 0.f && x0 < (float)NW) ? wxa0 : 0.f;
                wxa1 = (x1 >= 0.f && x1 < (float)NW) ? wxa1 : 0.f;
                wya0 = (y0 >= 0.f && y0 < (float)NH) ? wya0 : 0.f;
                wya1 = (y1 >= 0.f && y1 < (float)NH) ? wya1 : 0.f;
                wza0 = (z0 >= 0.f && z0 < (float)ND) ? wza0 : 0.f;
                wza1 = (z1 >= 0.f && z1 < (float)ND) ? wza1 : 0.f;

                int xi0 = min(max((int)x0, 0), NW - 1), xi1 = min(max((int)x1, 0), NW - 1);
                int yi0 = min(max((int)y0, 0), NH - 1), yi1 = min(max((int)y1, 0), NH - 1);
                int zi0 = min(max((int)z0, 0), ND - 1), zi1 = min(max((int)z1, 0), ND - 1);
                int o00 = (zi0 * NH + yi0) * NW, o01 = (zi0 * NH + yi1) * NW;
                int o10 = (zi1 * NH + yi0) * NW, o11 = (zi1 * NH + yi1) * NW;

                const int sb = (s * NVIN + v) * (DHW * NC * 4);   // slab, bytes

                // corner order k = dz*4 + dy*2 + dx (same as R3/R5/R6)
                f32x4 w0 = { (wxa0*wya0)*wza0, (wxa1*wya0)*wza0,
                             (wxa0*wya1)*wza0, (wxa1*wya1)*wza0 };
                f32x4 w1 = { (wxa0*wya0)*wza1, (wxa1*wya0)*wza1,
                             (wxa0*wya1)*wza1, (wxa1*wya1)*wza1 };
                i32x4 o0 = { sb + (o00 + xi0) * 64, sb + (o00 + xi1) * 64,
                             sb + (o01 + xi0) * 64, sb + (o01 + xi1) * 64 };
                i32x4 o1 = { sb + (o10 + xi0) * 64, sb + (o10 + xi1) * 64,
                             sb + (o11 + xi0) * 64, sb + (o11 + xi1) * 64 };

                *(f32x4*)(row + v*16 + 0)  = w0;
                *(f32x4*)(row + v*16 + 4)  = w1;
                *(i32x4*)(row + v*16 + 8)  = o0;
                *(i32x4*)(row + v*16 + 12) = o1;
            }
        }
        WAVE_LDS_SYNC();   // this wave's geometry visible to its own lanes

        // ---- phase 2: quad-cooperative loads, 8-deep via inline asm ----
        #pragma unroll 1
        for (int pass = 0; pass < 2; pass++) {
            const int sl = pass * 16 + (lane >> 2);     // 0..31 local sample
            const float* row = wslice + sl * 52;
            f32x4 acc = {0.f, 0.f, 0.f, 0.f};

            #pragma unroll
            for (int v = 0; v < NVIN; v++) {
                f32x4 wq0 = *(const f32x4*)(row + v*16 + 0);
                f32x4 wq1 = *(const f32x4*)(row + v*16 + 4);
                i32x4 oq0 = *(const i32x4*)(row + v*16 + 8);
                i32x4 oq1 = *(const i32x4*)(row + v*16 + 12);

                f32x4 a0, a1, a2, a3, a4, a5, a6, a7;
                int v0 = oq0.x + cb, v1 = oq0.y + cb, v2 = oq0.z + cb, v3 = oq0.w + cb;
                int v4 = oq1.x + cb, v5 = oq1.y + cb, v6 = oq1.z + cb, v7 = oq1.w + cb;
                asm volatile("global_load_dwordx4 %0, %1, %2" : "=&v"(a0) : "v"(v0), "s"(enc_t));
                asm volatile("global_load_dwordx4 %0, %1, %2" : "=&v"(a1) : "v"(v1), "s"(enc_t));
                asm volatile("global_load_dwordx4 %0, %1, %2" : "=&v"(a2) : "v"(v2), "s"(enc_t));
                asm volatile("global_load_dwordx4 %0, %1, %2" : "=&v"(a3) : "v"(v3), "s"(enc_t));
                asm volatile("global_load_dwordx4 %0, %1, %2" : "=&v"(a4) : "v"(v4), "s"(enc_t));
                asm volatile("global_load_dwordx4 %0, %1, %2" : "=&v"(a5) : "v"(v5), "s"(enc_t));
                asm volatile("global_load_dwordx4 %0, %1, %2" : "=&v"(a6) : "v"(v6), "s"(enc_t));
                asm volatile("global_load_dwordx4 %0, %1, %2" : "=&v"(a7) : "v"(v7), "s"(enc_t));
                asm volatile("s_waitcnt vmcnt(0)" ::: "memory");
                __builtin_amdgcn_sched_barrier(0);   // rule-18: pin FMAs after wait

                acc += wq0.x * a0;  acc += wq0.y * a1;
                acc += wq0.z * a2;  acc += wq0.w * a3;
                acc += wq1.x * a4;  acc += wq1.y * a5;
                acc += wq1.z * a6;  acc += wq1.w * a7;
            }
            ((f32x4*)xbuf)[(ray * 64 + h * 32 + sl) * 4 + c4] = acc * inv3;
        }
    }
}

// ---------------------------------------------------------------------------
// MFMA MLP + composite (R7-verified pipeline, A-frags from global xbuf).
// R7 change: ONE WAVE PER BLOCK (64 threads, 9.2 KB LDS) — raises the LDS
// occupancy ceiling 16 -> 17 waves/CU, finer dispatch granularity (18432
// blocks), zero inter-wave coupling. R2's wave-local lgkmcnt sync kept.
// ---------------------------------------------------------------------------
__global__ __launch_bounds__(64) void mlp_kernel(
    const float* __restrict__ xbuf,
    const float* __restrict__ znear_p,
    const float* __restrict__ zfar_p,
    const short* __restrict__ whi, const short* __restrict__ wlo,
    const float* __restrict__ B1, const float* __restrict__ B2,
    const float* __restrict__ B3,
    float* __restrict__ rhalf)
{
    const int lane = threadIdx.x & 63;
    const int ray  = blockIdx.x;
    const int px   = ray % HWH;
    const int py   = (ray / HWH) % HWH;
    const int b    = ray / (HWH * HWH);

    const float znear = znear_p[0];
    const float zfar  = zfar_p[0];

    __shared__ float sbuf[64][36];      // per-wave 64x36 staging (9.2 KB)
    float (*B)[36] = sbuf;
    const int li = lane & 15, q = lane >> 4;
    const float* X = xbuf + (size_t)ray * 64 * NC;   // this ray's 64x16 rows

    float b1v[4], b2v[4], b3v[2];
    #pragma unroll
    for (int nt = 0; nt < 4; nt++) { b1v[nt] = B1[nt*16 + li]; b2v[nt] = B2[nt*16 + li]; }
    b3v[0] = B3[li];
    b3v[1] = (li == 0) ? B3[16] : 0.f;

    // layer-1 A-frags straight from global X (K=16; q>=2 lanes are zero pad)
    bfrag xah[4], xal[4];
    bfrag zb = {0,0,0,0,0,0,0,0};
    #pragma unroll
    for (int mt = 0; mt < 4; mt++) {
        if (q < 2) mk_frag(X + (mt*16 + li) * NC + q * 8, xah[mt], xal[mt]);
        else { xah[mt] = zb; xal[mt] = zb; }
    }

    cfrag zc = {0.f, 0.f, 0.f, 0.f};
    cfrag h2acc[4][4];
    #pragma unroll
    for (int mt = 0; mt < 4; mt++)
        #pragma unroll
        for (int nt = 0; nt < 4; nt++) h2acc[mt][nt] = zc;

    #pragma unroll
    for (int c1 = 0; c1 < 2; c1++) {
        cfrag h1[4][2];
        #pragma unroll
        for (int nt2 = 0; nt2 < 2; nt2++) {
            int f = 2*c1 + nt2;
            bfrag bh = *(const bfrag*)(whi + (f*64 + lane)*8);
            bfrag bl = *(const bfrag*)(wlo + (f*64 + lane)*8);
            #pragma unroll
            for (int mt = 0; mt < 4; mt++) {
                cfrag a = zc;
                a = MFMA16(xal[mt], bh, a, 0, 0, 0);
                a = MFMA16(xah[mt], bl, a, 0, 0, 0);
                a = MFMA16(xah[mt], bh, a, 0, 0, 0);
                h1[mt][nt2] = a;
            }
        }
        WAVE_LDS_SYNC();   // prior iter's staging reads ordered before writes
        #pragma unroll
        for (int mt = 0; mt < 4; mt++)
            #pragma unroll
            for (int nt2 = 0; nt2 < 2; nt2++)
                #pragma unroll
                for (int r = 0; r < 4; r++)
                    B[mt*16 + q*4 + r][nt2*16 + li] =
                        fmaxf(h1[mt][nt2][r] + b1v[2*c1 + nt2], 0.f);
        WAVE_LDS_SYNC();   // this wave's writes visible to its own reads
        bfrag hah[4], hal[4];
        #pragma unroll
        for (int mt = 0; mt < 4; mt++)
            mk_frag(&B[mt*16 + li][q*8], hah[mt], hal[mt]);
        #pragma unroll
        for (int nt = 0; nt < 4; nt++) {
            int f = 4 + c1*4 + nt;
            bfrag bh = *(const bfrag*)(whi + (f*64 + lane)*8);
            bfrag bl = *(const bfrag*)(wlo + (f*64 + lane)*8);
            #pragma unroll
            for (int mt = 0; mt < 4; mt++) {
                cfrag a = h2acc[mt][nt];
                a = MFMA16(hal[mt], bh, a, 0, 0, 0);
                a = MFMA16(hah[mt], bl, a, 0, 0, 0);
                a = MFMA16(hah[mt], bh, a, 0, 0, 0);
                h2acc[mt][nt] = a;
            }
        }
    }

    cfrag oacc[4][2];
    #pragma unroll
    for (int mt = 0; mt < 4; mt++)
        #pragma unroll
        for (int nt = 0; nt < 2; nt++) oacc[mt][nt] = zc;

    #pragma unroll
    for (int c2 = 0; c2 < 2; c2++) {
        WAVE_LDS_SYNC();
        #pragma unroll
        for (int mt = 0; mt < 4; mt++)
            #pragma unroll
            for (int nt2 = 0; nt2 < 2; nt2++)
                #pragma unroll
                for (int r = 0; r < 4; r++)
                    B[mt*16 + q*4 + r][nt2*16 + li] =
                        fmaxf(h2acc[mt][2*c2 + nt2][r] + b2v[2*c2 + nt2], 0.f);
        WAVE_LDS_SYNC();
        bfrag hah[4], hal[4];
        #pragma unroll
        for (int mt = 0; mt < 4; mt++)
            mk_frag(&B[mt*16 + li][q*8], hah[mt], hal[mt]);
        #pragma unroll
        for (int nt = 0; nt < 2; nt++) {
            int f = 12 + c2*2 + nt;
            bfrag bh = *(const bfrag*)(whi + (f*64 + lane)*8);
            bfrag bl = *(const bfrag*)(wlo + (f*64 + lane)*8);
            #pragma unroll
            for (int mt = 0; mt < 4; mt++) {
                cfrag a = oacc[mt][nt];
                a = MFMA16(hal[mt], bh, a, 0, 0, 0);
                a = MFMA16(hah[mt], bl, a, 0, 0, 0);
                a = MFMA16(hah[mt], bh, a, 0, 0, 0);
                oacc[mt][nt] = a;
            }
        }
    }

    // O (C-layout) -> LDS -> per-lane (lane = its own sample row)
    WAVE_LDS_SYNC();
    #pragma unroll
    for (int mt = 0; mt < 4; mt++)
        #pragma unroll
        for (int nt = 0; nt < 2; nt++) {
            int ch = nt*16 + li;
            if (ch < 17) {
                #pragma unroll
                for (int r = 0; r < 4; r++)
                    B[mt*16 + q*4 + r][ch] = oacc[mt][nt][r] + b3v[nt];
            }
        }
    WAVE_LDS_SYNC();
    float4 o0 = *(float4*)&B[lane][0];
    float4 o1 = *(float4*)&B[lane][4];
    float4 o2 = *(float4*)&B[lane][8];
    float4 o3 = *(float4*)&B[lane][12];
    float o16 = B[lane][16];

    float density = fmaxf(o0.x, 0.f);
    float orgb[16] = {o0.y, o0.z, o0.w, o1.x, o1.y, o1.z, o1.w, o2.x,
                      o2.y, o2.z, o2.w, o3.x, o3.y, o3.z, o3.w, o16};

    // feats re-read from L2-hot xbuf (saves 16 live VGPRs across the MLP)
    float4 fx0 = *(const float4*)(X + lane * NC + 0);
    float4 fx1 = *(const float4*)(X + lane * NC + 4);
    float4 fx2 = *(const float4*)(X + lane * NC + 8);
    float4 fx3 = *(const float4*)(X + lane * NC + 12);
    float feats[16] = {fx0.x, fx0.y, fx0.z, fx0.w, fx1.x, fx1.y, fx1.z, fx1.w,
                       fx2.x, fx2.y, fx2.z, fx2.w, fx3.x, fx3.y, fx3.z, fx3.w};

    // ---- per-ray compositing ----
    float tv = znear + (zfar - znear) * ((float)lane / (float)(SPR - 1));
    float tn = znear + (zfar - znear) * ((float)(lane + 1) / (float)(SPR - 1));
    float delta = (lane < SPR - 1) ? (tn - tv) : 1e10f;
    float sigdel = density * delta;
    float alpha = 1.f - expf(-sigdel);
    float csum = sigdel;
    #pragma unroll
    for (int off = 1; off < 64; off <<= 1) {
        float nb = __shfl_up(csum, off, 64);
        if (lane >= off) csum += nb;
    }
    float wray = alpha * expf(-csum);

    #pragma unroll
    for (int c = 0; c < NC; c++) {
        float val = wray * (feats[c] + orgb[c]);
        #pragma unroll
        for (int off = 32; off >= 1; off >>= 1)
            val += __shfl_down(val, off, 64);
        if (lane == 0)
            rhalf[((b * NC + c) * HWH + py) * HWH + px] = val;
    }
}

// ---------------------------------------------------------------------------
// Scalar fallback (R6-proven) — only if ws too small.
// ---------------------------------------------------------------------------
__device__ __forceinline__ void mlp_and_composite(
    const float feats[NC], int lane, int b, int py, int px,
    float tv, float znear, float zfar,
    const float* __restrict__ W1, const float* __restrict__ B1,
    const float* __restrict__ W2, const float* __restrict__ B2,
    const float* __restrict__ W3, const float* __restrict__ B3,
    float* __restrict__ rhalf)
{
    float outa[17];
    #pragma unroll
    for (int c = 0; c < 17; c++) outa[c] = B3[c];
    for (int kc = 0; kc < 4; kc++) {
        float h2c[16];
        #pragma unroll
        for (int k = 0; k < 16; k++) h2c[k] = B2[kc * 16 + k];
        #pragma unroll 4
        for (int j = 0; j < 64; j++) {
            float a = B1[j];
            #pragma unroll
            for (int i = 0; i < NC; i++) a += feats[i] * W1[i * 64 + j];
            a = fmaxf(a, 0.f);
            const float* w2p = W2 + j * 64 + kc * 16;
            #pragma unroll
            for (int k = 0; k < 16; k++) h2c[k] += a * w2p[k];
        }
        #pragma unroll
        for (int k = 0; k < 16; k++) {
            float hv = fmaxf(h2c[k], 0.f);
            const float* w3p = W3 + (kc * 16 + k) * 17;
            #pragma unroll
            for (int c = 0; c < 17; c++) outa[c] += hv * w3p[c];
        }
    }
    float density = fmaxf(outa[0], 0.f);
    float tn = znear + (zfar - znear) * ((float)(lane + 1) / (float)(SPR - 1));
    float delta = (lane < SPR - 1) ? (tn - tv) : 1e10f;
    float sigdel = density * delta;
    float alpha = 1.f - expf(-sigdel);
    float csum = sigdel;
    #pragma unroll
    for (int off = 1; off < 64; off <<= 1) {
        float nb = __shfl_up(csum, off, 64);
        if (lane >= off) csum += nb;
    }
    float wray = alpha * expf(-csum);
    #pragma unroll
    for (int c = 0; c < NC; c++) {
        float val = wray * (feats[c] + outa[1 + c]);
        #pragma unroll
        for (int off = 32; off >= 1; off >>= 1)
            val += __shfl_down(val, off, 64);
        if (lane == 0)
            rhalf[((b * NC + c) * HWH + py) * HWH + px] = val;
    }
}

__global__ __launch_bounds__(256) void render_kernel(
    const float* __restrict__ enc,
    const float* __restrict__ ipose,
    const float* __restrict__ tpose,
    const float* __restrict__ focal_p,
    const float* __restrict__ znear_p,
    const float* __restrict__ zfar_p,
    const float* __restrict__ W1, const float* __restrict__ B1,
    const float* __restrict__ W2, const float* __restrict__ B2,
    const float* __restrict__ W3, const float* __restrict__ B3,
    float* __restrict__ rhalf)
{
    const int lane = threadIdx.x & 63;
    const int ray  = blockIdx.x * 4 + (threadIdx.x >> 6);
    const int px   = ray % HWH;
    const int py   = (ray / HWH) % HWH;
    const int b    = ray / (HWH * HWH);
    const int s    = b >> 2;
    const float focal = focal_p[0];
    const float znear = znear_p[0];
    const float zfar  = zfar_p[0];
    const float* P = tpose + b * 16;
    float ysc = ((py + 0.5f) / (float)HWH) * 2.f - 1.f;
    float xsc = ((px + 0.5f) / (float)HWH) * 2.f - 1.f;
    float dcx = xsc / focal, dcy = -ysc / focal, dcz = -1.f;
    float dirx = P[0]*dcx + P[1]*dcy + P[2]*dcz;
    float diry = P[4]*dcx + P[5]*dcy + P[6]*dcz;
    float dirz = P[8]*dcx + P[9]*dcy + P[10]*dcz;
    float tv  = znear + (zfar - znear) * ((float)lane / (float)(SPR - 1));
    float ptx = P[3] + tv * dirx, pty = P[7] + tv * diry, ptz = P[11] + tv * dirz;
    float feats[NC];
    #pragma unroll
    for (int c = 0; c < NC; c++) feats[c] = 0.f;
    const float minz = focal * znear, maxz = focal * zfar;
    for (int v = 0; v < NVIN; v++) {
        const float* E = ipose + (s * NVIN + v) * 16;
        float qx = ptx - E[3], qy = pty - E[7], qz = ptz - E[11];
        float lx = E[0]*qx + E[4]*qy + E[8]*qz;
        float ly = E[1]*qx + E[5]*qy + E[9]*qz;
        float lz = E[2]*qx + E[6]*qy + E[10]*qz;
        float zz = -lz;
        float u  = lx / zz * focal;
        float vv = ly / zz * focal;
        float wd = 2.f * (zz - minz) / (maxz - minz) - 1.f;
        float ix = ((u   + 1.f) * NW - 1.f) * 0.5f;
        float iy = ((-vv + 1.f) * NH - 1.f) * 0.5f;
        float iz = ((-wd + 1.f) * ND - 1.f) * 0.5f;
        float x0 = floorf(ix), y0 = floorf(iy), z0 = floorf(iz);
        float wgt[8]; int idx[8];
        #pragma unroll
        for (int k = 0; k < 8; k++) {
            float xc = x0 + (k & 1), yc = y0 + ((k >> 1) & 1), zc = z0 + (k >> 2);
            float wt = (1.f - fabsf(ix - xc)) * (1.f - fabsf(iy - yc)) * (1.f - fabsf(iz - zc));
            bool valid = (xc >= 0.f) && (xc < (float)NW) &&
                         (yc >= 0.f) && (yc < (float)NH) &&
                         (zc >= 0.f) && (zc < (float)ND);
            wgt[k] = valid ? wt : 0.f;
            int xi = min(max((int)xc, 0), NW - 1);
            int yi = min(max((int)yc, 0), NH - 1);
            int zi = min(max((int)zc, 0), ND - 1);
            idx[k] = (zi * NH + yi) * NW + xi;
        }
        const float* VB = enc + (size_t)(s * NVIN + v) * NC * DHW;
        #pragma unroll
        for (int c = 0; c < NC; c++) {
            const float* vc = VB + c * DHW;
            float acc = 0.f;
            #pragma unroll
            for (int k = 0; k < 8; k++) acc += wgt[k] * vc[idx[k]];
            feats[c] += acc;
        }
    }
    #pragma unroll
    for (int c = 0; c < NC; c++) feats[c] *= (1.f / 3.f);
    mlp_and_composite(feats, lane, b, py, px, tv, znear, zfar,
                      W1, B1, W2, B2, W3, B3, rhalf);
}

// 2x bilinear upsample, align_corners=True.
__global__ __launch_bounds__(256) void upsample_kernel(
    const float* __restrict__ in, float* __restrict__ out)
{
    int tid = blockIdx.x * 256 + threadIdx.x;
    int ox = tid % NW;
    int oy = (tid / NW) % NH;
    int c  = (tid / (NW * NH)) % NC;
    int b  = tid / (NW * NH * NC);
    const float sc = (float)((HWH - 1) / (double)(NH - 1)); // 47/95
    float pyf = oy * sc;
    float pxf = ox * sc;
    int y0 = (int)floorf(pyf); int y1 = min(y0 + 1, HWH - 1); float fy = pyf - y0;
    int x0 = (int)floorf(pxf); int x1 = min(x0 + 1, HWH - 1); float fx = pxf - x0;
    const float* src = in + (b * NC + c) * HWH * HWH;
    float v00 = src[y0 * HWH + x0], v01 = src[y0 * HWH + x1];
    float v10 = src[y1 * HWH + x0], v11 = src[y1 * HWH + x1];
    float gl = v00 * (1.f - fy) + v10 * fy;
    float gr = v01 * (1.f - fy) + v11 * fy;
    out[tid] = gl * (1.f - fx) + gr * fx;
}

extern "C" void kernel_launch(void* const* d_in, const int* in_sizes, int n_in,
                              void* d_out, int out_size, void* d_ws, size_t ws_size,
                              hipStream_t stream) {
    const float* enc   = (const float*)d_in[0];
    const float* ipose = (const float*)d_in[1];
    const float* tpose = (const float*)d_in[2];
    const float* focal = (const float*)d_in[3];
    const float* znear = (const float*)d_in[4];
    const float* zfar  = (const float*)d_in[5];
    const float* W1 = (const float*)d_in[7];
    const float* B1 = (const float*)d_in[8];
    const float* W2 = (const float*)d_in[9];
    const float* B2 = (const float*)d_in[10];
    const float* W3 = (const float*)d_in[11];
    const float* B3 = (const float*)d_in[12];

    float* out = (float*)d_out;
    const int nrays = NRAYS;                             // 18432
    const int nout  = NS * NVT * NC * NH * NW;           // 1179648
    const size_t enc_t_bytes = (size_t)NS * NVIN * NC * DHW * 4;   // 226.5 MB
    const size_t rhalf_bytes = (size_t)nrays * NC * 4;             // 1.18 MB
    const size_t wfrag_bytes = 16 * 64 * 8 * sizeof(short);        // 16 KB
    const size_t xbuf_bytes  = (size_t)NSAMP * NC * 4;             // 75.5 MB

    if (ws_size >= enc_t_bytes + rhalf_bytes + 2 * wfrag_bytes + xbuf_bytes) {
        char* base = (char*)d_ws;
        float* enc_t = (float*)base;                      base += enc_t_bytes;
        float* rhalf = (float*)base;                      base += rhalf_bytes;
        short* whi   = (short*)base;                      base += wfrag_bytes;
        short* wlo   = (short*)base;                      base += wfrag_bytes;
        float* xbuf  = (float*)base;

        wprep_kernel<<<4, 256, 0, stream>>>(W1, W2, W3, whi, wlo);
        transpose_kernel<<<NS * NVIN * NTILE, 256, 0, stream>>>(enc, enc_t);
        gather_kernel<<<nrays / 4, 256, 0, stream>>>(
            enc_t, ipose, tpose, focal, znear, zfar, xbuf);
        mlp_kernel<<<nrays, 64, 0, stream>>>(
            xbuf, znear, zfar, whi, wlo, B1, B2, B3, rhalf);
        upsample_kernel<<<nout / 256, 256, 0, stream>>>(rhalf, out);
    } else {
        float* rhalf = (float*)d_ws;
        render_kernel<<<nrays / 4, 256, 0, stream>>>(
            enc, ipose, tpose, focal, znear, zfar,
            W1, B1, W2, B2, W3, B3, rhalf);
        upsample_kernel<<<nout / 256, 256, 0, stream>>>(rhalf, out);
    }
}